// Round 1
// baseline (980.839 us; speedup 1.0000x reference)
//
#include <hip/hip_runtime.h>
#include <math.h>

#define Bv  64
#define Tv  512
#define Dv  256
#define FFv 512
#define Lv  4
#define BTv (Bv*Tv)
#define EPSv 1e-5f
#define RS32 0.17677669529663687f   // 1/sqrt(32)

typedef __attribute__((ext_vector_type(8))) short short8;
typedef __attribute__((ext_vector_type(4))) float f32x4;
typedef unsigned short us;

__device__ __forceinline__ us f2bf(float f) {
    union { float f; unsigned u; } v; v.f = f;
    unsigned u = v.u + 0x7FFFu + ((v.u >> 16) & 1u);   // RNE
    return (us)(u >> 16);
}
__device__ __forceinline__ unsigned pk2(float a, float b) {
    return ((unsigned)f2bf(b) << 16) | (unsigned)f2bf(a);
}
__device__ __forceinline__ float wave_sum(float v) {
#pragma unroll
    for (int o = 32; o > 0; o >>= 1) v += __shfl_xor(v, o);
    return v;
}

// ---------------- all weight converts in one launch -------------------------
__global__ __launch_bounds__(256) void cvtall_kernel(
    const float* __restrict__ qw, const float* __restrict__ ow,
    const float* __restrict__ f1, const float* __restrict__ f2,
    const float* __restrict__ qb,
    us* __restrict__ wq, us* __restrict__ wo, us* __restrict__ w1,
    us* __restrict__ w2, float* __restrict__ sb)
{
    int blk = blockIdx.x, tid = threadIdx.x;
    if (blk < 2048) {
        const float* s; us* d; int i; float sc = 1.0f;
        if (blk < 768)       { i = blk*256 + tid;        s = qw; d = wq;
                               sc = (((i >> 6) % 768) < 256) ? RS32 : 1.0f; }
        else if (blk < 1024) { i = (blk-768)*256 + tid;  s = ow; d = wo; }
        else if (blk < 1536) { i = (blk-1024)*256 + tid; s = f1; d = w1; }
        else                 { i = (blk-1536)*256 + tid; s = f2; d = w2; }
        float4 v = ((const float4*)s)[i];
        ushort4 o;
        o.x = f2bf(v.x*sc); o.y = f2bf(v.y*sc); o.z = f2bf(v.z*sc); o.w = f2bf(v.w*sc);
        ((ushort4*)d)[i] = o;
    } else {
        int i = (blk-2048)*256 + tid;
        sb[i] = qb[i] * (((i % 768) < 256) ? RS32 : 1.0f);
    }
}

// ---------------- embed + LN: block = one row ------------------------------
__global__ __launch_bounds__(256) void embed_ln_kernel(
    const float* __restrict__ lat, const int* __restrict__ mids,
    const float* __restrict__ pos, const float* __restrict__ ef,
    const float* __restrict__ et,  const float* __restrict__ ep,
    const float* __restrict__ nw,  const float* __restrict__ nb,
    float* __restrict__ x, us* __restrict__ xn)
{
    int bt = blockIdx.x;
    int d  = threadIdx.x;
    int t  = bt & (Tv - 1);
    int id = mids[bt];
    int promo = id >> 12;
    int rem   = id & 4095;
    int frm   = rem >> 6;
    int to    = rem & 63;
    size_t o = (size_t)bt * Dv + d;
    float xv = lat[o] + pos[t*Dv + d] + ef[frm*Dv + d] + et[to*Dv + d] + ep[promo*Dv + d];
    x[o] = xv;
    __shared__ float rs[4], rq[4];
    int wv = d >> 6, lane = d & 63;
    float s  = wave_sum(xv);
    float sq = wave_sum(xv*xv);
    if (lane == 0) { rs[wv] = s; rq[wv] = sq; }
    __syncthreads();
    float mu  = (rs[0]+rs[1]+rs[2]+rs[3]) * (1.0f/Dv);
    float var = (rq[0]+rq[1]+rq[2]+rq[3]) * (1.0f/Dv) - mu*mu;
    float inv = rsqrtf(var + EPSv);
    xn[o] = f2bf((xv - mu)*inv*nw[d] + nb[d]);
}

// ---------------- final: LN + mask select (fp32 out) ------------------------
__global__ __launch_bounds__(256) void final_kernel(
    const float* __restrict__ x, const float* __restrict__ lat,
    const int* __restrict__ mask, const float* __restrict__ w,
    const float* __restrict__ b, float* __restrict__ out)
{
    int wv = threadIdx.x >> 6, lane = threadIdx.x & 63;
    size_t row = (size_t)blockIdx.x * 4 + wv;
    float4 v = ((const float4*)(x + row*Dv))[lane];
    float mu = wave_sum(v.x + v.y + v.z + v.w) * (1.0f/Dv);
    float dx = v.x-mu, dy = v.y-mu, dz = v.z-mu, dw = v.w-mu;
    float var = wave_sum(dx*dx + dy*dy + dz*dz + dw*dw) * (1.0f/Dv);
    float inv = rsqrtf(var + EPSv);
    float4 w4 = ((const float4*)w)[lane];
    float4 b4 = ((const float4*)b)[lane];
    float4 o;
    o.x = dx*inv*w4.x + b4.x;
    o.y = dy*inv*w4.y + b4.y;
    o.z = dz*inv*w4.z + b4.z;
    o.w = dw*inv*w4.w + b4.w;
    if (!mask[row]) o = ((const float4*)(lat + row*Dv))[lane];
    ((float4*)(out + row*Dv))[lane] = o;
}

// ---------------- bf16 MFMA GEMM (128x128 tile, BK=64, XOR-swizzled LDS) ----
template<int RELU>
__global__ __launch_bounds__(256) void mm_kernel(
    const us* __restrict__ A, const us* __restrict__ B,
    const float* __restrict__ bias, us* __restrict__ C,
    int M, int N, int K)
{
    __shared__ us As[128*64];
    __shared__ us Bs[128*64];
    int tid  = threadIdx.x;
    int lane = tid & 63;
    int wu   = __builtin_amdgcn_readfirstlane(tid >> 6);
    int m0 = blockIdx.x * 128, n0 = blockIdx.y * 128;
    int wm = wu & 1, wn = wu >> 1;
    f32x4 acc[4][4] = {};
    int srow = lane >> 3;
    int sg   = (lane & 7) ^ srow;
    const us* Ag = A + (size_t)m0 * K + sg*8;
    const us* Bg = B + (size_t)n0 * K + sg*8;
    int cc = lane & 15, q4 = lane >> 4;
    for (int k0 = 0; k0 < K; k0 += 64) {
        __syncthreads();
#pragma unroll
        for (int p = 0; p < 4; p++) {
            int row = wu*32 + p*8;
            __builtin_amdgcn_global_load_lds(
                (const __attribute__((address_space(1))) unsigned int*)(Ag + (size_t)(row + srow)*K + k0),
                (__attribute__((address_space(3))) unsigned int*)(As + row*64),
                16, 0, 0);
            __builtin_amdgcn_global_load_lds(
                (const __attribute__((address_space(1))) unsigned int*)(Bg + (size_t)(row + srow)*K + k0),
                (__attribute__((address_space(3))) unsigned int*)(Bs + row*64),
                16, 0, 0);
        }
        __syncthreads();
#pragma unroll
        for (int h = 0; h < 2; h++) {
            int pg = ((h*4 + q4) ^ (cc & 7)) * 8;
            short8 av[4], bv[4];
#pragma unroll
            for (int i = 0; i < 4; i++)
                av[i] = *(const short8*)(As + (wm*64 + i*16 + cc)*64 + pg);
#pragma unroll
            for (int j = 0; j < 4; j++)
                bv[j] = *(const short8*)(Bs + (wn*64 + j*16 + cc)*64 + pg);
#pragma unroll
            for (int i = 0; i < 4; i++)
#pragma unroll
                for (int j = 0; j < 4; j++)
                    acc[i][j] = __builtin_amdgcn_mfma_f32_16x16x32_bf16(av[i], bv[j], acc[i][j], 0, 0, 0);
        }
    }
#pragma unroll
    for (int j = 0; j < 4; j++) {
        int n = n0 + wn*64 + j*16 + cc;
        float bj = bias[n];
#pragma unroll
        for (int i = 0; i < 4; i++) {
#pragma unroll
            for (int r = 0; r < 4; r++) {
                int m = m0 + wm*64 + i*16 + q4*4 + r;
                float v = acc[i][j][r] + bj;
                if (RELU) v = fmaxf(v, 0.f);
                C[(size_t)m * N + n] = f2bf(v);
            }
        }
    }
}

// ---------------- GEMM 64x256 tile (BK=64, swizzled) + residual + fused LN --
__global__ __launch_bounds__(256) void mm256_kernel(
    const us* __restrict__ A, const us* __restrict__ B,
    const float* __restrict__ bias, float* __restrict__ x,
    us* __restrict__ xn, const float* __restrict__ nw,
    const float* __restrict__ nb, int M, int K)
{
    __shared__ us As[64*64];
    __shared__ us Bs[256*64];
    __shared__ float red[64][4][2];
    __shared__ float mus[64], rss[64];
    int tid  = threadIdx.x;
    int lane = tid & 63;
    int wu   = __builtin_amdgcn_readfirstlane(tid >> 6);
    int m0 = blockIdx.x * 64;
    f32x4 acc[4][4] = {};
    int srow = lane >> 3;
    int sg   = (lane & 7) ^ srow;
    const us* Ag = A + (size_t)m0 * K + sg*8;
    const us* Bg = B + sg*8;
    int cc = lane & 15, q4 = lane >> 4;
    for (int k0 = 0; k0 < K; k0 += 64) {
        __syncthreads();
#pragma unroll
        for (int p = 0; p < 2; p++) {
            int row = wu*16 + p*8;
            __builtin_amdgcn_global_load_lds(
                (const __attribute__((address_space(1))) unsigned int*)(Ag + (size_t)(row + srow)*K + k0),
                (__attribute__((address_space(3))) unsigned int*)(As + row*64),
                16, 0, 0);
        }
#pragma unroll
        for (int p = 0; p < 8; p++) {
            int row = wu*64 + p*8;
            __builtin_amdgcn_global_load_lds(
                (const __attribute__((address_space(1))) unsigned int*)(Bg + (size_t)(row + srow)*K + k0),
                (__attribute__((address_space(3))) unsigned int*)(Bs + row*64),
                16, 0, 0);
        }
        __syncthreads();
#pragma unroll
        for (int h = 0; h < 2; h++) {
            int pg = ((h*4 + q4) ^ (cc & 7)) * 8;
            short8 av[4], bv[4];
#pragma unroll
            for (int i = 0; i < 4; i++)
                av[i] = *(const short8*)(As + (i*16 + cc)*64 + pg);
#pragma unroll
            for (int j = 0; j < 4; j++)
                bv[j] = *(const short8*)(Bs + (wu*64 + j*16 + cc)*64 + pg);
#pragma unroll
            for (int i = 0; i < 4; i++)
#pragma unroll
                for (int j = 0; j < 4; j++)
                    acc[i][j] = __builtin_amdgcn_mfma_f32_16x16x32_bf16(av[i], bv[j], acc[i][j], 0, 0, 0);
        }
    }
    float bb[4], nwv[4], nbv[4];
#pragma unroll
    for (int j = 0; j < 4; j++) {
        int n = wu*64 + j*16 + cc;
        bb[j] = bias[n]; nwv[j] = nw[n]; nbv[j] = nb[n];
    }
#pragma unroll
    for (int i = 0; i < 4; i++) {
        float s[4] = {0.f,0.f,0.f,0.f}, sq[4] = {0.f,0.f,0.f,0.f};
#pragma unroll
        for (int j = 0; j < 4; j++) {
#pragma unroll
            for (int r = 0; r < 4; r++) {
                int m = m0 + i*16 + q4*4 + r;
                size_t off = (size_t)m * Dv + wu*64 + j*16 + cc;
                float v = acc[i][j][r] + bb[j] + x[off];
                acc[i][j][r] = v;
                x[off] = v;
                s[r] += v; sq[r] += v*v;
            }
        }
#pragma unroll
        for (int r = 0; r < 4; r++) {
#pragma unroll
            for (int o = 1; o < 16; o <<= 1) {
                s[r]  += __shfl_xor(s[r],  o);
                sq[r] += __shfl_xor(sq[r], o);
            }
        }
        if (cc == 0) {
#pragma unroll
            for (int r = 0; r < 4; r++) {
                red[i*16 + q4*4 + r][wu][0] = s[r];
                red[i*16 + q4*4 + r][wu][1] = sq[r];
            }
        }
    }
    __syncthreads();
    if (tid < 64) {
        float ts = red[tid][0][0] + red[tid][1][0] + red[tid][2][0] + red[tid][3][0];
        float tq = red[tid][0][1] + red[tid][1][1] + red[tid][2][1] + red[tid][3][1];
        float mu = ts * (1.0f/Dv);
        float var = tq * (1.0f/Dv) - mu*mu;
        mus[tid] = mu;
        rss[tid] = rsqrtf(var + EPSv);
    }
    __syncthreads();
#pragma unroll
    for (int i = 0; i < 4; i++) {
#pragma unroll
        for (int r = 0; r < 4; r++) {
            int ml = i*16 + q4*4 + r;
            float mu = mus[ml], rv = rss[ml];
#pragma unroll
            for (int j = 0; j < 4; j++) {
                size_t off = (size_t)(m0 + ml) * Dv + wu*64 + j*16 + cc;
                xn[off] = f2bf((acc[i][j][r] - mu)*rv*nwv[j] + nbv[j]);
            }
        }
    }
}

// ---------------- fused FFN: x += relu(xn@W1^T+b1)@W2^T+b2 ; xn = LN(x) -----
// REWRITE: weights (W1,W2) are L2-resident (512KB/layer shared by all 512
// blocks) -> feed MFMA B-operands (and phase-1 A) DIRECTLY from global as
// register fragments. No gload_lds staging, no per-k-tile barriers. LDS holds
// only h1 (64x520 bf16 = 66.5KB) -> 2 blocks/CU (was 1 at 100.8KB). Barriers:
// 3 total (was ~26). __launch_bounds__(512,4) caps VGPR at 128 so both
// 8-wave blocks fit (16 waves/CU = 4/SIMD).
__global__ __launch_bounds__(512, 4) void ffn_kernel(
    const us* __restrict__ W1, const float* __restrict__ b1,
    const us* __restrict__ W2, const float* __restrict__ b2,
    float* __restrict__ x, us* xn,
    const float* __restrict__ nw, const float* __restrict__ nb)
{
    __shared__ us h1s[64*520];          // 66.5KB, +8 pad keeps reads ~conflict-free
    __shared__ float red[64][2][2];
    __shared__ float mus[64], rss[64];

    int tid  = threadIdx.x;
    int lane = tid & 63;
    int wu   = __builtin_amdgcn_readfirstlane(tid >> 6);   // 0..7
    int m0   = blockIdx.x * 64;
    int cc = lane & 15, q4 = lane >> 4;
    int rw  = (wu & 3) * 16;        // row base (both phases)
    int cw  = (wu >> 2) * 256;      // phase1 col base
    int cw2 = (wu >> 2) * 128;      // phase2 col base

    // ---- phase 1: h1 = relu(xn @ W1^T + b1), operands direct from global ----
    // A-frags: row (m0+rw+cc), full K=256 preloaded once (8 x short8 = 32 VGPR)
    short8 av[8];
    {
        const us* xrow = xn + (size_t)(m0 + rw + cc) * 256 + q4*8;
#pragma unroll
        for (int t = 0; t < 8; t++)
            av[t] = *(const short8*)(xrow + t*32);
    }
    {
        const us* w1p = W1 + (size_t)(cw + cc) * 256 + q4*8;
#pragma unroll 4
        for (int jj = 0; jj < 16; jj++) {
            f32x4 acc = {0.f, 0.f, 0.f, 0.f};
#pragma unroll
            for (int t = 0; t < 8; t++) {
                short8 bf = *(const short8*)(w1p + (size_t)jj*16*256 + t*32);
                acc = __builtin_amdgcn_mfma_f32_16x16x32_bf16(av[t], bf, acc, 0, 0, 0);
            }
            int n = cw + jj*16 + cc;
            float bb = b1[n];
#pragma unroll
            for (int r = 0; r < 4; r++) {
                float v = fmaxf(acc[r] + bb, 0.f);
                h1s[(rw + q4*4 + r)*520 + n] = f2bf(v);
            }
        }
    }
    __syncthreads();        // all h1 tiles visible (col-partner wave wrote half our rows)

    // ---- phase 2: out = h1 @ W2^T + b2 (K=512, split in two 256-halves) ----
    f32x4 acc2[8] = {};
    {
        const us* w2p = W2 + (size_t)(cw2 + cc) * 512 + q4*8;
#pragma unroll
        for (int kh = 0; kh < 2; kh++) {
            short8 af[8];
#pragma unroll
            for (int t = 0; t < 8; t++)
                af[t] = *(const short8*)(h1s + (rw + cc)*520 + kh*256 + t*32 + q4*8);
            for (int j2 = 0; j2 < 8; j2++) {
#pragma unroll
                for (int t = 0; t < 8; t++) {
                    short8 bf = *(const short8*)(w2p + (size_t)j2*16*512 + kh*256 + t*32);
                    acc2[j2] = __builtin_amdgcn_mfma_f32_16x16x32_bf16(af[t], bf, acc2[j2], 0, 0, 0);
                }
            }
        }
    }

    // ---- epilogue: residual + x write + fused LN -> xn ----
    float bb2[8], nwv[8], nbv[8];
#pragma unroll
    for (int j2 = 0; j2 < 8; j2++) {
        int n = cw2 + j2*16 + cc;
        bb2[j2] = b2[n]; nwv[j2] = nw[n]; nbv[j2] = nb[n];
    }
    float s[4] = {0.f,0.f,0.f,0.f}, sq[4] = {0.f,0.f,0.f,0.f};
#pragma unroll
    for (int j2 = 0; j2 < 8; j2++) {
#pragma unroll
        for (int r = 0; r < 4; r++) {
            size_t off = (size_t)(m0 + rw + q4*4 + r) * Dv + cw2 + j2*16 + cc;
            float v = acc2[j2][r] + bb2[j2] + x[off];
            acc2[j2][r] = v;
            x[off] = v;
            s[r] += v; sq[r] += v*v;
        }
    }
#pragma unroll
    for (int r = 0; r < 4; r++) {
#pragma unroll
        for (int o = 1; o < 16; o <<= 1) {
            s[r]  += __shfl_xor(s[r],  o);
            sq[r] += __shfl_xor(sq[r], o);
        }
    }
    if (cc == 0) {
#pragma unroll
        for (int r = 0; r < 4; r++) {
            red[rw + q4*4 + r][wu >> 2][0] = s[r];
            red[rw + q4*4 + r][wu >> 2][1] = sq[r];
        }
    }
    __syncthreads();
    if (tid < 64) {
        float ts = red[tid][0][0] + red[tid][1][0];
        float tq = red[tid][0][1] + red[tid][1][1];
        float mu = ts * (1.0f/Dv);
        float var = tq * (1.0f/Dv) - mu*mu;
        mus[tid] = mu;
        rss[tid] = rsqrtf(var + EPSv);
    }
    __syncthreads();
#pragma unroll
    for (int r = 0; r < 4; r++) {
        int ml = rw + q4*4 + r;
        float mu = mus[ml], rv = rss[ml];
#pragma unroll
        for (int j2 = 0; j2 < 8; j2++) {
            size_t off = (size_t)(m0 + ml) * Dv + cw2 + j2*16 + cc;
            xn[off] = f2bf((acc2[j2][r] - mu)*rv*nwv[j2] + nbv[j2]);
        }
    }
}

// ---------------- MFMA flash attention (S^T form, 2-deep pipelined) ---------
// XCD-aware decode: b = blk&63 so XCD (blk%8) hosts a fixed b%8 slice ->
// K/V working set per XCD ~ L2-sized.
__global__ __launch_bounds__(256) void attn_kernel(
    const us* __restrict__ qkv, us* __restrict__ ao)
{
    int blk = blockIdx.x;
    int b  = blk & 63;
    int h  = (blk >> 6) & 7;
    int qt = blk >> 9;
    int i0 = qt << 6;
    int tid = threadIdx.x;
    int lane = tid & 63;
    int wu = tid >> 6;

    __shared__ us Ks[2][64][40];
    __shared__ us Vt[2][32][72];
    __shared__ us Ps[4][16][72];
    __shared__ float Ls[4][16];

    size_t rowbase = (size_t)b * Tv;
    int c = lane & 15, q4 = lane >> 4;

    short8 qfrag = *(const short8*)(qkv + (rowbase + i0 + wu*16 + c)*768 + h*32 + q4*8);

    int skey = tid >> 2, sdc = (tid & 3) << 3;
    int vkey = tid & 63, vg = tid >> 6;
    const us* kgp = qkv + (rowbase + skey)*768 + 256 + h*32 + sdc;
    const us* vgp = qkv + (rowbase + vkey)*768 + 512 + h*32 + vg*8;

    f32x4 oacc[2] = {};
    float lsum = 0.f;
    int ntiles = qt + 1;

    short8 kreg = *(const short8*)(kgp);
    short8 vreg = *(const short8*)(vgp);
    *(short8*)&Ks[0][skey][sdc] = kreg;
#pragma unroll
    for (int j = 0; j < 8; j++) Vt[0][vg*8 + j][vkey] = vreg[j];
    if (ntiles > 1) {
        kreg = *(const short8*)(kgp + 64*768);
        vreg = *(const short8*)(vgp + 64*768);
    }
    __syncthreads();

    for (int kt = 0; kt < ntiles; kt++) {
        int cur = kt & 1;
        if (kt + 1 < ntiles) {
            *(short8*)&Ks[cur^1][skey][sdc] = kreg;
#pragma unroll
            for (int j = 0; j < 8; j++) Vt[cur^1][vg*8 + j][vkey] = vreg[j];
        }
        if (kt + 2 < ntiles) {
            kreg = *(const short8*)(kgp + (size_t)(kt+2)*64*768);
            vreg = *(const short8*)(vgp + (size_t)(kt+2)*64*768);
        }

        f32x4 st[4];
#pragma unroll
        for (int jt = 0; jt < 4; jt++) {
            short8 kf = *(const short8*)&Ks[cur][jt*16 + c][q4*8];
            st[jt] = __builtin_amdgcn_mfma_f32_16x16x32_bf16(kf, qfrag, (f32x4){0.f,0.f,0.f,0.f}, 0, 0, 0);
        }
        bool diag = (kt == ntiles - 1);
#pragma unroll
        for (int jt = 0; jt < 4; jt++) {
            float msk = (!diag || (2*jt + (q4 >> 1) <= 2*wu + (c >> 3))) ? 1.f : 0.f;
            float p0 = __expf(st[jt][0]) * msk;
            float p1 = __expf(st[jt][1]) * msk;
            float p2 = __expf(st[jt][2]) * msk;
            float p3 = __expf(st[jt][3]) * msk;
            lsum += p0 + p1 + p2 + p3;
            uint2 w2; w2.x = pk2(p0, p1); w2.y = pk2(p2, p3);
            *(uint2*)&Ps[wu][c][jt*16 + q4*4] = w2;
        }
#pragma unroll
        for (int kk = 0; kk < 2; kk++) {
            short8 pf = *(const short8*)&Ps[wu][c][kk*32 + q4*8];
#pragma unroll
            for (int dt = 0; dt < 2; dt++) {
                short8 vf = *(const short8*)&Vt[cur][dt*16 + c][kk*32 + q4*8];
                oacc[dt] = __builtin_amdgcn_mfma_f32_16x16x32_bf16(pf, vf, oacc[dt], 0, 0, 0);
            }
        }
        __syncthreads();
    }

    float l = lsum;
    l += __shfl_xor(l, 16);
    l += __shfl_xor(l, 32);
    if (q4 == 0) Ls[wu][c] = 1.0f / l;
    float4 lv4 = *(const float4*)&Ls[wu][q4*4];
#pragma unroll
    for (int dt = 0; dt < 2; dt++) {
#pragma unroll
        for (int r = 0; r < 4; r++) {
            float li = (r == 0) ? lv4.x : (r == 1) ? lv4.y : (r == 2) ? lv4.z : lv4.w;
            ao[(rowbase + i0 + wu*16 + q4*4 + r)*256 + h*32 + dt*16 + c] = f2bf(oacc[dt][r] * li);
        }
    }
}

// ---------------- launch ----------------------------------------------------
extern "C" void kernel_launch(void* const* d_in, const int* in_sizes, int n_in,
                              void* d_out, int out_size, void* d_ws, size_t ws_size,
                              hipStream_t stream)
{
    const float* latents    = (const float*)d_in[0];
    const int*   move_ids   = (const int*)  d_in[1];
    const int*   mask       = (const int*)  d_in[2];
    const float* positional = (const float*)d_in[3];
    const float* embed_from = (const float*)d_in[4];
    const float* embed_to   = (const float*)d_in[5];
    const float* embed_promo= (const float*)d_in[6];
    const float* in_proj_w  = (const float*)d_in[7];
    const float* in_proj_b  = (const float*)d_in[8];
    const float* out_w      = (const float*)d_in[9];
    const float* out_b      = (const float*)d_in[10];
    const float* fc1_w      = (const float*)d_in[11];
    const float* fc1_b      = (const float*)d_in[12];
    const float* fc2_w      = (const float*)d_in[13];
    const float* fc2_b      = (const float*)d_in[14];
    const float* norm_w     = (const float*)d_in[15];
    const float* norm_b     = (const float*)d_in[16];
    float* out = (float*)d_out;

    float* x   = (float*)d_ws;                              // BT*256 f32
    float* sb  = x + (size_t)BTv * Dv;                      // L*768 f32
    us* xn  = (us*)(sb + Lv*768);                           // BT*256 bf16
    us* qkv = xn + (size_t)BTv * Dv;                        // BT*768
    us* ao  = qkv + (size_t)BTv * 768;                      // BT*256
    us* h1  = ao + (size_t)BTv * Dv;                        // BT*512 (unused now)
    us* wq  = h1 + (size_t)BTv * FFv;                       // L*768*256
    us* wo  = wq + (size_t)Lv * 768 * Dv;
    us* w1  = wo + (size_t)Lv * Dv * Dv;
    us* w2  = w1 + (size_t)Lv * FFv * Dv;

    cvtall_kernel<<<2060, 256, 0, stream>>>(in_proj_w, out_w, fc1_w, fc2_w,
                                            in_proj_b, wq, wo, w1, w2, sb);

    embed_ln_kernel<<<BTv, 256, 0, stream>>>(latents, move_ids, positional,
        embed_from, embed_to, embed_promo, norm_w, norm_b, x, xn);

    for (int l = 0; l < Lv; l++) {
        mm_kernel<0><<<dim3(BTv/128, 768/128), 256, 0, stream>>>(
            xn, wq + (size_t)l*768*Dv, sb + l*768, qkv, BTv, 768, Dv);
        attn_kernel<<<Bv*8*(Tv/64), 256, 0, stream>>>(qkv, ao);
        mm256_kernel<<<BTv/64, 256, 0, stream>>>(
            ao, wo + (size_t)l*Dv*Dv, out_b + l*Dv, x, xn, norm_w, norm_b,
            BTv, Dv);
        ffn_kernel<<<BTv/64, 512, 0, stream>>>(
            w1 + (size_t)l*FFv*Dv, fc1_b + l*FFv,
            w2 + (size_t)l*Dv*FFv, fc2_b + l*Dv,
            x, xn, norm_w, norm_b);
    }
    final_kernel<<<BTv/4, 256, 0, stream>>>(x, latents, mask, norm_w, norm_b, out);
}

// Round 2
// 676.222 us; speedup vs baseline: 1.4505x; 1.4505x over previous
//
#include <hip/hip_runtime.h>
#include <math.h>

#define Bv  64
#define Tv  512
#define Dv  256
#define FFv 512
#define Lv  4
#define BTv (Bv*Tv)
#define EPSv 1e-5f
#define RS32 0.17677669529663687f   // 1/sqrt(32)

typedef __attribute__((ext_vector_type(8))) short short8;
typedef __attribute__((ext_vector_type(4))) float f32x4;
typedef unsigned short us;

__device__ __forceinline__ us f2bf(float f) {
    union { float f; unsigned u; } v; v.f = f;
    unsigned u = v.u + 0x7FFFu + ((v.u >> 16) & 1u);   // RNE
    return (us)(u >> 16);
}
__device__ __forceinline__ unsigned pk2(float a, float b) {
    return ((unsigned)f2bf(b) << 16) | (unsigned)f2bf(a);
}
__device__ __forceinline__ float wave_sum(float v) {
#pragma unroll
    for (int o = 32; o > 0; o >>= 1) v += __shfl_xor(v, o);
    return v;
}

// ---------------- all weight converts in one launch -------------------------
__global__ __launch_bounds__(256) void cvtall_kernel(
    const float* __restrict__ qw, const float* __restrict__ ow,
    const float* __restrict__ f1, const float* __restrict__ f2,
    const float* __restrict__ qb,
    us* __restrict__ wq, us* __restrict__ wo, us* __restrict__ w1,
    us* __restrict__ w2, float* __restrict__ sb)
{
    int blk = blockIdx.x, tid = threadIdx.x;
    if (blk < 2048) {
        const float* s; us* d; int i; float sc = 1.0f;
        if (blk < 768)       { i = blk*256 + tid;        s = qw; d = wq;
                               sc = (((i >> 6) % 768) < 256) ? RS32 : 1.0f; }
        else if (blk < 1024) { i = (blk-768)*256 + tid;  s = ow; d = wo; }
        else if (blk < 1536) { i = (blk-1024)*256 + tid; s = f1; d = w1; }
        else                 { i = (blk-1536)*256 + tid; s = f2; d = w2; }
        float4 v = ((const float4*)s)[i];
        ushort4 o;
        o.x = f2bf(v.x*sc); o.y = f2bf(v.y*sc); o.z = f2bf(v.z*sc); o.w = f2bf(v.w*sc);
        ((ushort4*)d)[i] = o;
    } else {
        int i = (blk-2048)*256 + tid;
        sb[i] = qb[i] * (((i % 768) < 256) ? RS32 : 1.0f);
    }
}

// ---------------- embed + LN: block = one row ------------------------------
__global__ __launch_bounds__(256) void embed_ln_kernel(
    const float* __restrict__ lat, const int* __restrict__ mids,
    const float* __restrict__ pos, const float* __restrict__ ef,
    const float* __restrict__ et,  const float* __restrict__ ep,
    const float* __restrict__ nw,  const float* __restrict__ nb,
    float* __restrict__ x, us* __restrict__ xn)
{
    int bt = blockIdx.x;
    int d  = threadIdx.x;
    int t  = bt & (Tv - 1);
    int id = mids[bt];
    int promo = id >> 12;
    int rem   = id & 4095;
    int frm   = rem >> 6;
    int to    = rem & 63;
    size_t o = (size_t)bt * Dv + d;
    float xv = lat[o] + pos[t*Dv + d] + ef[frm*Dv + d] + et[to*Dv + d] + ep[promo*Dv + d];
    x[o] = xv;
    __shared__ float rs[4], rq[4];
    int wv = d >> 6, lane = d & 63;
    float s  = wave_sum(xv);
    float sq = wave_sum(xv*xv);
    if (lane == 0) { rs[wv] = s; rq[wv] = sq; }
    __syncthreads();
    float mu  = (rs[0]+rs[1]+rs[2]+rs[3]) * (1.0f/Dv);
    float var = (rq[0]+rq[1]+rq[2]+rq[3]) * (1.0f/Dv) - mu*mu;
    float inv = rsqrtf(var + EPSv);
    xn[o] = f2bf((xv - mu)*inv*nw[d] + nb[d]);
}

// ---------------- final: LN + mask select (fp32 out) ------------------------
__global__ __launch_bounds__(256) void final_kernel(
    const float* __restrict__ x, const float* __restrict__ lat,
    const int* __restrict__ mask, const float* __restrict__ w,
    const float* __restrict__ b, float* __restrict__ out)
{
    int wv = threadIdx.x >> 6, lane = threadIdx.x & 63;
    size_t row = (size_t)blockIdx.x * 4 + wv;
    float4 v = ((const float4*)(x + row*Dv))[lane];
    float mu = wave_sum(v.x + v.y + v.z + v.w) * (1.0f/Dv);
    float dx = v.x-mu, dy = v.y-mu, dz = v.z-mu, dw = v.w-mu;
    float var = wave_sum(dx*dx + dy*dy + dz*dz + dw*dw) * (1.0f/Dv);
    float inv = rsqrtf(var + EPSv);
    float4 w4 = ((const float4*)w)[lane];
    float4 b4 = ((const float4*)b)[lane];
    float4 o;
    o.x = dx*inv*w4.x + b4.x;
    o.y = dy*inv*w4.y + b4.y;
    o.z = dz*inv*w4.z + b4.z;
    o.w = dw*inv*w4.w + b4.w;
    if (!mask[row]) o = ((const float4*)(lat + row*Dv))[lane];
    ((float4*)(out + row*Dv))[lane] = o;
}

// ---------------- bf16 MFMA GEMM (128x128 tile, BK=64, XOR-swizzled LDS) ----
template<int RELU>
__global__ __launch_bounds__(256) void mm_kernel(
    const us* __restrict__ A, const us* __restrict__ B,
    const float* __restrict__ bias, us* __restrict__ C,
    int M, int N, int K)
{
    __shared__ us As[128*64];
    __shared__ us Bs[128*64];
    int tid  = threadIdx.x;
    int lane = tid & 63;
    int wu   = __builtin_amdgcn_readfirstlane(tid >> 6);
    int m0 = blockIdx.x * 128, n0 = blockIdx.y * 128;
    int wm = wu & 1, wn = wu >> 1;
    f32x4 acc[4][4] = {};
    int srow = lane >> 3;
    int sg   = (lane & 7) ^ srow;
    const us* Ag = A + (size_t)m0 * K + sg*8;
    const us* Bg = B + (size_t)n0 * K + sg*8;
    int cc = lane & 15, q4 = lane >> 4;
    for (int k0 = 0; k0 < K; k0 += 64) {
        __syncthreads();
#pragma unroll
        for (int p = 0; p < 4; p++) {
            int row = wu*32 + p*8;
            __builtin_amdgcn_global_load_lds(
                (const __attribute__((address_space(1))) unsigned int*)(Ag + (size_t)(row + srow)*K + k0),
                (__attribute__((address_space(3))) unsigned int*)(As + row*64),
                16, 0, 0);
            __builtin_amdgcn_global_load_lds(
                (const __attribute__((address_space(1))) unsigned int*)(Bg + (size_t)(row + srow)*K + k0),
                (__attribute__((address_space(3))) unsigned int*)(Bs + row*64),
                16, 0, 0);
        }
        __syncthreads();
#pragma unroll
        for (int h = 0; h < 2; h++) {
            int pg = ((h*4 + q4) ^ (cc & 7)) * 8;
            short8 av[4], bv[4];
#pragma unroll
            for (int i = 0; i < 4; i++)
                av[i] = *(const short8*)(As + (wm*64 + i*16 + cc)*64 + pg);
#pragma unroll
            for (int j = 0; j < 4; j++)
                bv[j] = *(const short8*)(Bs + (wn*64 + j*16 + cc)*64 + pg);
#pragma unroll
            for (int i = 0; i < 4; i++)
#pragma unroll
                for (int j = 0; j < 4; j++)
                    acc[i][j] = __builtin_amdgcn_mfma_f32_16x16x32_bf16(av[i], bv[j], acc[i][j], 0, 0, 0);
        }
    }
#pragma unroll
    for (int j = 0; j < 4; j++) {
        int n = n0 + wn*64 + j*16 + cc;
        float bj = bias[n];
#pragma unroll
        for (int i = 0; i < 4; i++) {
#pragma unroll
            for (int r = 0; r < 4; r++) {
                int m = m0 + wm*64 + i*16 + q4*4 + r;
                float v = acc[i][j][r] + bj;
                if (RELU) v = fmaxf(v, 0.f);
                C[(size_t)m * N + n] = f2bf(v);
            }
        }
    }
}

// ---------------- GEMM 64x256 tile (BK=64, swizzled) + residual + fused LN --
__global__ __launch_bounds__(256) void mm256_kernel(
    const us* __restrict__ A, const us* __restrict__ B,
    const float* __restrict__ bias, float* __restrict__ x,
    us* __restrict__ xn, const float* __restrict__ nw,
    const float* __restrict__ nb, int M, int K)
{
    __shared__ us As[64*64];
    __shared__ us Bs[256*64];
    __shared__ float red[64][4][2];
    __shared__ float mus[64], rss[64];
    int tid  = threadIdx.x;
    int lane = tid & 63;
    int wu   = __builtin_amdgcn_readfirstlane(tid >> 6);
    int m0 = blockIdx.x * 64;
    f32x4 acc[4][4] = {};
    int srow = lane >> 3;
    int sg   = (lane & 7) ^ srow;
    const us* Ag = A + (size_t)m0 * K + sg*8;
    const us* Bg = B + sg*8;
    int cc = lane & 15, q4 = lane >> 4;
    for (int k0 = 0; k0 < K; k0 += 64) {
        __syncthreads();
#pragma unroll
        for (int p = 0; p < 2; p++) {
            int row = wu*16 + p*8;
            __builtin_amdgcn_global_load_lds(
                (const __attribute__((address_space(1))) unsigned int*)(Ag + (size_t)(row + srow)*K + k0),
                (__attribute__((address_space(3))) unsigned int*)(As + row*64),
                16, 0, 0);
        }
#pragma unroll
        for (int p = 0; p < 8; p++) {
            int row = wu*64 + p*8;
            __builtin_amdgcn_global_load_lds(
                (const __attribute__((address_space(1))) unsigned int*)(Bg + (size_t)(row + srow)*K + k0),
                (__attribute__((address_space(3))) unsigned int*)(Bs + row*64),
                16, 0, 0);
        }
        __syncthreads();
#pragma unroll
        for (int h = 0; h < 2; h++) {
            int pg = ((h*4 + q4) ^ (cc & 7)) * 8;
            short8 av[4], bv[4];
#pragma unroll
            for (int i = 0; i < 4; i++)
                av[i] = *(const short8*)(As + (i*16 + cc)*64 + pg);
#pragma unroll
            for (int j = 0; j < 4; j++)
                bv[j] = *(const short8*)(Bs + (wu*64 + j*16 + cc)*64 + pg);
#pragma unroll
            for (int i = 0; i < 4; i++)
#pragma unroll
                for (int j = 0; j < 4; j++)
                    acc[i][j] = __builtin_amdgcn_mfma_f32_16x16x32_bf16(av[i], bv[j], acc[i][j], 0, 0, 0);
        }
    }
    float bb[4], nwv[4], nbv[4];
#pragma unroll
    for (int j = 0; j < 4; j++) {
        int n = wu*64 + j*16 + cc;
        bb[j] = bias[n]; nwv[j] = nw[n]; nbv[j] = nb[n];
    }
#pragma unroll
    for (int i = 0; i < 4; i++) {
        float s[4] = {0.f,0.f,0.f,0.f}, sq[4] = {0.f,0.f,0.f,0.f};
#pragma unroll
        for (int j = 0; j < 4; j++) {
#pragma unroll
            for (int r = 0; r < 4; r++) {
                int m = m0 + i*16 + q4*4 + r;
                size_t off = (size_t)m * Dv + wu*64 + j*16 + cc;
                float v = acc[i][j][r] + bb[j] + x[off];
                acc[i][j][r] = v;
                x[off] = v;
                s[r] += v; sq[r] += v*v;
            }
        }
#pragma unroll
        for (int r = 0; r < 4; r++) {
#pragma unroll
            for (int o = 1; o < 16; o <<= 1) {
                s[r]  += __shfl_xor(s[r],  o);
                sq[r] += __shfl_xor(sq[r], o);
            }
        }
        if (cc == 0) {
#pragma unroll
            for (int r = 0; r < 4; r++) {
                red[i*16 + q4*4 + r][wu][0] = s[r];
                red[i*16 + q4*4 + r][wu][1] = sq[r];
            }
        }
    }
    __syncthreads();
    if (tid < 64) {
        float ts = red[tid][0][0] + red[tid][1][0] + red[tid][2][0] + red[tid][3][0];
        float tq = red[tid][0][1] + red[tid][1][1] + red[tid][2][1] + red[tid][3][1];
        float mu = ts * (1.0f/Dv);
        float var = tq * (1.0f/Dv) - mu*mu;
        mus[tid] = mu;
        rss[tid] = rsqrtf(var + EPSv);
    }
    __syncthreads();
#pragma unroll
    for (int i = 0; i < 4; i++) {
#pragma unroll
        for (int r = 0; r < 4; r++) {
            int ml = i*16 + q4*4 + r;
            float mu = mus[ml], rv = rss[ml];
#pragma unroll
            for (int j = 0; j < 4; j++) {
                size_t off = (size_t)(m0 + ml) * Dv + wu*64 + j*16 + cc;
                xn[off] = f2bf((acc[i][j][r] - mu)*rv*nwv[j] + nbv[j]);
            }
        }
    }
}

// ---------------- fused FFN: x += relu(xn@W1^T+b1)@W2^T+b2 ; xn = LN(x) -----
// v2: T3 minimal 2-phase pipeline. A-operands (xn rows) live in registers
// (loaded once at kernel start, latency hidden under W staging). W1/W2 staged
// into double-buffered 32KB LDS n-chunks via global_load_lds: STAGE(c+1) is
// issued BEFORE compute(c), so each __syncthreads()'s vmcnt(0) drain waits on
// loads issued a full compute-segment earlier (latency hidden). One barrier
// per chunk (16 total vs round-0's ~26 serial ones). Each chunk completes the
// full K reduction, so h1 relu+store folds into the chunk loop and phase-2
// accumulators finalize per chunk. LDS = 2x32KB Wbuf + 66.5KB h1 = 132KB ->
// 1 block/CU, 8 waves, internally pipelined.
__global__ __launch_bounds__(512) void ffn_kernel(
    const us* __restrict__ W1, const float* __restrict__ b1,
    const us* __restrict__ W2, const float* __restrict__ b2,
    float* __restrict__ x, us* xn,
    const float* __restrict__ nw, const float* __restrict__ nb)
{
    __shared__ us Wb[2][64*256];        // 2 x 32KB weight chunk (dbuf)
    __shared__ us h1s[64*520];          // 66.5KB h1 (pad 520 -> 2-way-free reads)
    __shared__ float red[64][2][2];
    __shared__ float mus[64], rss[64];

    int tid  = threadIdx.x;
    int lane = tid & 63;
    int wu   = __builtin_amdgcn_readfirstlane(tid >> 6);   // 0..7
    int m0   = blockIdx.x * 64;
    int cc = lane & 15, q4 = lane >> 4;
    int rw = (wu & 3) * 16;             // token-row base for this wave
    int ng = wu >> 2;                   // n-subgroup 0/1
    int srow = lane >> 3;
    int sg   = (lane & 7) ^ srow;       // pre-swizzled source k-group

    // W1 chunk c (64 n-rows x 256 k) -> Wb[d] as 4 swizzled [64][64] k-tiles.
    // 32 gload_lds x 1KB; idx = wu*4+j -> kt = idx>>3, p = idx&7.
#define STAGE_W1(c, d) { \
    _Pragma("unroll") \
    for (int j = 0; j < 4; j++) { \
        int idx = wu*4 + j; \
        int kt = idx >> 3, p = idx & 7; \
        __builtin_amdgcn_global_load_lds( \
            (const __attribute__((address_space(1))) unsigned int*)(W1 + (size_t)((c)*64 + p*8 + srow)*256 + kt*64 + sg*8), \
            (__attribute__((address_space(3))) unsigned int*)(&Wb[d][kt*4096 + p*512]), \
            16, 0, 0); \
    } }

    // W2 chunk c (32 n-rows x 512 k) -> Wb[d] as 8 swizzled [32][64] k-tiles.
#define STAGE_W2(c, d) { \
    _Pragma("unroll") \
    for (int j = 0; j < 4; j++) { \
        int idx = wu*4 + j; \
        int kt = idx >> 2, p = idx & 3; \
        __builtin_amdgcn_global_load_lds( \
            (const __attribute__((address_space(1))) unsigned int*)(W2 + (size_t)((c)*32 + p*8 + srow)*512 + kt*64 + sg*8), \
            (__attribute__((address_space(3))) unsigned int*)(&Wb[d][kt*2048 + p*512]), \
            16, 0, 0); \
    } }

    // ---- prologue: A-frags (xn rows, full K=256) -> regs; stage W1 chunk 0 --
    short8 av[8];
    {
        const us* xrow = xn + (size_t)(m0 + rw + cc) * 256 + q4*8;
#pragma unroll
        for (int t = 0; t < 8; t++)
            av[t] = *(const short8*)(xrow + t*32);
    }
    STAGE_W1(0, 0);
    __syncthreads();

    // ---- phase 1: h1 = relu(xn @ W1^T + b1), 8 pipelined n-chunks ----------
    int cur = 0;
    for (int c = 0; c < 8; c++) {
        if (c < 7) STAGE_W1(c + 1, cur ^ 1);
#pragma unroll
        for (int jj2 = 0; jj2 < 2; jj2++) {
            int brow = ng*32 + jj2*16 + cc;          // chunk-local W1 row
            f32x4 acc = {0.f, 0.f, 0.f, 0.f};
#pragma unroll
            for (int kt = 0; kt < 4; kt++) {
#pragma unroll
                for (int h = 0; h < 2; h++) {
                    int pg = ((h*4 + q4) ^ (cc & 7)) * 8;
                    short8 bf = *(const short8*)(&Wb[cur][kt*4096 + brow*64 + pg]);
                    acc = __builtin_amdgcn_mfma_f32_16x16x32_bf16(av[kt*2 + h], bf, acc, 0, 0, 0);
                }
            }
            int n = c*64 + ng*32 + jj2*16 + cc;
            float bb = b1[n];
#pragma unroll
            for (int r = 0; r < 4; r++) {
                float v = fmaxf(acc[r] + bb, 0.f);
                h1s[(rw + q4*4 + r)*520 + n] = f2bf(v);
            }
        }
        __syncthreads();
        cur ^= 1;
    }

    // ---- inter-phase: h1 A-frags -> regs; stage W2 chunk 0 -----------------
    STAGE_W2(0, 0);
    short8 af[16];
#pragma unroll
    for (int t = 0; t < 16; t++)
        af[t] = *(const short8*)(h1s + (rw + cc)*520 + t*32 + q4*8);
    __syncthreads();

    // ---- phase 2: out = h1 @ W2^T + b2, 8 pipelined n-chunks ---------------
    f32x4 acc2[8] = {};
    cur = 0;
    for (int c2 = 0; c2 < 8; c2++) {
        if (c2 < 7) STAGE_W2(c2 + 1, cur ^ 1);
        int brow = ng*16 + cc;                       // chunk-local W2 row
        f32x4 a = {0.f, 0.f, 0.f, 0.f};
#pragma unroll
        for (int kt = 0; kt < 8; kt++) {
#pragma unroll
            for (int h = 0; h < 2; h++) {
                int pg = ((h*4 + q4) ^ (cc & 7)) * 8;
                short8 bf = *(const short8*)(&Wb[cur][kt*2048 + brow*64 + pg]);
                a = __builtin_amdgcn_mfma_f32_16x16x32_bf16(af[kt*2 + h], bf, a, 0, 0, 0);
            }
        }
        acc2[c2] = a;
        __syncthreads();
        cur ^= 1;
    }

    // ---- epilogue: residual + x write + fused LN -> xn ---------------------
    float bb2[8], nwv[8], nbv[8];
#pragma unroll
    for (int c2 = 0; c2 < 8; c2++) {
        int n = c2*32 + ng*16 + cc;
        bb2[c2] = b2[n]; nwv[c2] = nw[n]; nbv[c2] = nb[n];
    }
    float s[4] = {0.f,0.f,0.f,0.f}, sq[4] = {0.f,0.f,0.f,0.f};
#pragma unroll
    for (int c2 = 0; c2 < 8; c2++) {
#pragma unroll
        for (int r = 0; r < 4; r++) {
            size_t off = (size_t)(m0 + rw + q4*4 + r) * Dv + c2*32 + ng*16 + cc;
            float v = acc2[c2][r] + bb2[c2] + x[off];
            acc2[c2][r] = v;
            x[off] = v;
            s[r] += v; sq[r] += v*v;
        }
    }
#pragma unroll
    for (int r = 0; r < 4; r++) {
#pragma unroll
        for (int o = 1; o < 16; o <<= 1) {
            s[r]  += __shfl_xor(s[r],  o);
            sq[r] += __shfl_xor(sq[r], o);
        }
    }
    if (cc == 0) {
#pragma unroll
        for (int r = 0; r < 4; r++) {
            red[rw + q4*4 + r][ng][0] = s[r];
            red[rw + q4*4 + r][ng][1] = sq[r];
        }
    }
    __syncthreads();
    if (tid < 64) {
        float ts = red[tid][0][0] + red[tid][1][0];
        float tq = red[tid][0][1] + red[tid][1][1];
        float mu = ts * (1.0f/Dv);
        float var = tq * (1.0f/Dv) - mu*mu;
        mus[tid] = mu;
        rss[tid] = rsqrtf(var + EPSv);
    }
    __syncthreads();
#pragma unroll
    for (int r = 0; r < 4; r++) {
        int ml = rw + q4*4 + r;
        float mu = mus[ml], rv = rss[ml];
#pragma unroll
        for (int c2 = 0; c2 < 8; c2++) {
            size_t off = (size_t)(m0 + ml) * Dv + c2*32 + ng*16 + cc;
            xn[off] = f2bf((acc2[c2][r] - mu)*rv*nwv[c2] + nbv[c2]);
        }
    }
#undef STAGE_W1
#undef STAGE_W2
}

// ---------------- MFMA flash attention (S^T form, 2-deep pipelined) ---------
// XCD-aware decode: b = blk&63 so XCD (blk%8) hosts a fixed b%8 slice ->
// K/V working set per XCD ~ L2-sized.
__global__ __launch_bounds__(256) void attn_kernel(
    const us* __restrict__ qkv, us* __restrict__ ao)
{
    int blk = blockIdx.x;
    int b  = blk & 63;
    int h  = (blk >> 6) & 7;
    int qt = blk >> 9;
    int i0 = qt << 6;
    int tid = threadIdx.x;
    int lane = tid & 63;
    int wu = tid >> 6;

    __shared__ us Ks[2][64][40];
    __shared__ us Vt[2][32][72];
    __shared__ us Ps[4][16][72];
    __shared__ float Ls[4][16];

    size_t rowbase = (size_t)b * Tv;
    int c = lane & 15, q4 = lane >> 4;

    short8 qfrag = *(const short8*)(qkv + (rowbase + i0 + wu*16 + c)*768 + h*32 + q4*8);

    int skey = tid >> 2, sdc = (tid & 3) << 3;
    int vkey = tid & 63, vg = tid >> 6;
    const us* kgp = qkv + (rowbase + skey)*768 + 256 + h*32 + sdc;
    const us* vgp = qkv + (rowbase + vkey)*768 + 512 + h*32 + vg*8;

    f32x4 oacc[2] = {};
    float lsum = 0.f;
    int ntiles = qt + 1;

    short8 kreg = *(const short8*)(kgp);
    short8 vreg = *(const short8*)(vgp);
    *(short8*)&Ks[0][skey][sdc] = kreg;
#pragma unroll
    for (int j = 0; j < 8; j++) Vt[0][vg*8 + j][vkey] = vreg[j];
    if (ntiles > 1) {
        kreg = *(const short8*)(kgp + 64*768);
        vreg = *(const short8*)(vgp + 64*768);
    }
    __syncthreads();

    for (int kt = 0; kt < ntiles; kt++) {
        int cur = kt & 1;
        if (kt + 1 < ntiles) {
            *(short8*)&Ks[cur^1][skey][sdc] = kreg;
#pragma unroll
            for (int j = 0; j < 8; j++) Vt[cur^1][vg*8 + j][vkey] = vreg[j];
        }
        if (kt + 2 < ntiles) {
            kreg = *(const short8*)(kgp + (size_t)(kt+2)*64*768);
            vreg = *(const short8*)(vgp + (size_t)(kt+2)*64*768);
        }

        f32x4 st[4];
#pragma unroll
        for (int jt = 0; jt < 4; jt++) {
            short8 kf = *(const short8*)&Ks[cur][jt*16 + c][q4*8];
            st[jt] = __builtin_amdgcn_mfma_f32_16x16x32_bf16(kf, qfrag, (f32x4){0.f,0.f,0.f,0.f}, 0, 0, 0);
        }
        bool diag = (kt == ntiles - 1);
#pragma unroll
        for (int jt = 0; jt < 4; jt++) {
            float msk = (!diag || (2*jt + (q4 >> 1) <= 2*wu + (c >> 3))) ? 1.f : 0.f;
            float p0 = __expf(st[jt][0]) * msk;
            float p1 = __expf(st[jt][1]) * msk;
            float p2 = __expf(st[jt][2]) * msk;
            float p3 = __expf(st[jt][3]) * msk;
            lsum += p0 + p1 + p2 + p3;
            uint2 w2; w2.x = pk2(p0, p1); w2.y = pk2(p2, p3);
            *(uint2*)&Ps[wu][c][jt*16 + q4*4] = w2;
        }
#pragma unroll
        for (int kk = 0; kk < 2; kk++) {
            short8 pf = *(const short8*)&Ps[wu][c][kk*32 + q4*8];
#pragma unroll
            for (int dt = 0; dt < 2; dt++) {
                short8 vf = *(const short8*)&Vt[cur][dt*16 + c][kk*32 + q4*8];
                oacc[dt] = __builtin_amdgcn_mfma_f32_16x16x32_bf16(pf, vf, oacc[dt], 0, 0, 0);
            }
        }
        __syncthreads();
    }

    float l = lsum;
    l += __shfl_xor(l, 16);
    l += __shfl_xor(l, 32);
    if (q4 == 0) Ls[wu][c] = 1.0f / l;
    float4 lv4 = *(const float4*)&Ls[wu][q4*4];
#pragma unroll
    for (int dt = 0; dt < 2; dt++) {
#pragma unroll
        for (int r = 0; r < 4; r++) {
            float li = (r == 0) ? lv4.x : (r == 1) ? lv4.y : (r == 2) ? lv4.z : lv4.w;
            ao[(rowbase + i0 + wu*16 + q4*4 + r)*256 + h*32 + dt*16 + c] = f2bf(oacc[dt][r] * li);
        }
    }
}

// ---------------- launch ----------------------------------------------------
extern "C" void kernel_launch(void* const* d_in, const int* in_sizes, int n_in,
                              void* d_out, int out_size, void* d_ws, size_t ws_size,
                              hipStream_t stream)
{
    const float* latents    = (const float*)d_in[0];
    const int*   move_ids   = (const int*)  d_in[1];
    const int*   mask       = (const int*)  d_in[2];
    const float* positional = (const float*)d_in[3];
    const float* embed_from = (const float*)d_in[4];
    const float* embed_to   = (const float*)d_in[5];
    const float* embed_promo= (const float*)d_in[6];
    const float* in_proj_w  = (const float*)d_in[7];
    const float* in_proj_b  = (const float*)d_in[8];
    const float* out_w      = (const float*)d_in[9];
    const float* out_b      = (const float*)d_in[10];
    const float* fc1_w      = (const float*)d_in[11];
    const float* fc1_b      = (const float*)d_in[12];
    const float* fc2_w      = (const float*)d_in[13];
    const float* fc2_b      = (const float*)d_in[14];
    const float* norm_w     = (const float*)d_in[15];
    const float* norm_b     = (const float*)d_in[16];
    float* out = (float*)d_out;

    float* x   = (float*)d_ws;                              // BT*256 f32
    float* sb  = x + (size_t)BTv * Dv;                      // L*768 f32
    us* xn  = (us*)(sb + Lv*768);                           // BT*256 bf16
    us* qkv = xn + (size_t)BTv * Dv;                        // BT*768
    us* ao  = qkv + (size_t)BTv * 768;                      // BT*256
    us* h1  = ao + (size_t)BTv * Dv;                        // BT*512 (unused now)
    us* wq  = h1 + (size_t)BTv * FFv;                       // L*768*256
    us* wo  = wq + (size_t)Lv * 768 * Dv;
    us* w1  = wo + (size_t)Lv * Dv * Dv;
    us* w2  = w1 + (size_t)Lv * FFv * Dv;

    cvtall_kernel<<<2060, 256, 0, stream>>>(in_proj_w, out_w, fc1_w, fc2_w,
                                            in_proj_b, wq, wo, w1, w2, sb);

    embed_ln_kernel<<<BTv, 256, 0, stream>>>(latents, move_ids, positional,
        embed_from, embed_to, embed_promo, norm_w, norm_b, x, xn);

    for (int l = 0; l < Lv; l++) {
        mm_kernel<0><<<dim3(BTv/128, 768/128), 256, 0, stream>>>(
            xn, wq + (size_t)l*768*Dv, sb + l*768, qkv, BTv, 768, Dv);
        attn_kernel<<<Bv*8*(Tv/64), 256, 0, stream>>>(qkv, ao);
        mm256_kernel<<<BTv/64, 256, 0, stream>>>(
            ao, wo + (size_t)l*Dv*Dv, out_b + l*Dv, x, xn, norm_w, norm_b,
            BTv, Dv);
        ffn_kernel<<<BTv/64, 512, 0, stream>>>(
            w1 + (size_t)l*FFv*Dv, fc1_b + l*FFv,
            w2 + (size_t)l*Dv*FFv, fc2_b + l*Dv,
            x, xn, norm_w, norm_b);
    }
    final_kernel<<<BTv/4, 256, 0, stream>>>(x, latents, mask, norm_w, norm_b, out);
}

// Round 3
// 647.643 us; speedup vs baseline: 1.5145x; 1.0441x over previous
//
#include <hip/hip_runtime.h>
#include <math.h>

#define Bv  64
#define Tv  512
#define Dv  256
#define FFv 512
#define Lv  4
#define BTv (Bv*Tv)
#define EPSv 1e-5f
#define RS32 0.17677669529663687f   // 1/sqrt(32)

typedef __attribute__((ext_vector_type(8))) short short8;
typedef __attribute__((ext_vector_type(4))) float f32x4;
typedef unsigned short us;

__device__ __forceinline__ us f2bf(float f) {
    union { float f; unsigned u; } v; v.f = f;
    unsigned u = v.u + 0x7FFFu + ((v.u >> 16) & 1u);   // RNE
    return (us)(u >> 16);
}
__device__ __forceinline__ unsigned pk2(float a, float b) {
    return ((unsigned)f2bf(b) << 16) | (unsigned)f2bf(a);
}
__device__ __forceinline__ float wave_sum(float v) {
#pragma unroll
    for (int o = 32; o > 0; o >>= 1) v += __shfl_xor(v, o);
    return v;
}

// ---------------- all weight converts in one launch -------------------------
__global__ __launch_bounds__(256) void cvtall_kernel(
    const float* __restrict__ qw, const float* __restrict__ ow,
    const float* __restrict__ f1, const float* __restrict__ f2,
    const float* __restrict__ qb,
    us* __restrict__ wq, us* __restrict__ wo, us* __restrict__ w1,
    us* __restrict__ w2, float* __restrict__ sb)
{
    int blk = blockIdx.x, tid = threadIdx.x;
    if (blk < 2048) {
        const float* s; us* d; int i; float sc = 1.0f;
        if (blk < 768)       { i = blk*256 + tid;        s = qw; d = wq;
                               sc = (((i >> 6) % 768) < 256) ? RS32 : 1.0f; }
        else if (blk < 1024) { i = (blk-768)*256 + tid;  s = ow; d = wo; }
        else if (blk < 1536) { i = (blk-1024)*256 + tid; s = f1; d = w1; }
        else                 { i = (blk-1536)*256 + tid; s = f2; d = w2; }
        float4 v = ((const float4*)s)[i];
        ushort4 o;
        o.x = f2bf(v.x*sc); o.y = f2bf(v.y*sc); o.z = f2bf(v.z*sc); o.w = f2bf(v.w*sc);
        ((ushort4*)d)[i] = o;
    } else {
        int i = (blk-2048)*256 + tid;
        sb[i] = qb[i] * (((i % 768) < 256) ? RS32 : 1.0f);
    }
}

// ---------------- embed + LN: 4 rows/block, one wave per row, float4 --------
__global__ __launch_bounds__(256) void embed_ln_kernel(
    const float* __restrict__ lat, const int* __restrict__ mids,
    const float* __restrict__ pos, const float* __restrict__ ef,
    const float* __restrict__ et,  const float* __restrict__ ep,
    const float* __restrict__ nw,  const float* __restrict__ nb,
    float* __restrict__ x, us* __restrict__ xn)
{
    int wv = threadIdx.x >> 6, lane = threadIdx.x & 63;
    size_t row = (size_t)blockIdx.x * 4 + wv;
    int t  = (int)(row & (Tv - 1));
    int id = mids[row];
    int promo = id >> 12;
    int rem   = id & 4095;
    int frm   = rem >> 6;
    int to    = rem & 63;
    float4 v  = ((const float4*)(lat + row*Dv))[lane];
    float4 pv = ((const float4*)(pos + (size_t)t*Dv))[lane];
    float4 fv = ((const float4*)(ef + (size_t)frm*Dv))[lane];
    float4 tv = ((const float4*)(et + (size_t)to*Dv))[lane];
    float4 ev = ((const float4*)(ep + (size_t)promo*Dv))[lane];
    v.x += pv.x + fv.x + tv.x + ev.x;
    v.y += pv.y + fv.y + tv.y + ev.y;
    v.z += pv.z + fv.z + tv.z + ev.z;
    v.w += pv.w + fv.w + tv.w + ev.w;
    ((float4*)(x + row*Dv))[lane] = v;
    float mu = wave_sum(v.x + v.y + v.z + v.w) * (1.0f/Dv);
    float dx = v.x-mu, dy = v.y-mu, dz = v.z-mu, dw = v.w-mu;
    float var = wave_sum(dx*dx + dy*dy + dz*dz + dw*dw) * (1.0f/Dv);
    float inv = rsqrtf(var + EPSv);
    float4 w4 = ((const float4*)nw)[lane];
    float4 b4 = ((const float4*)nb)[lane];
    ushort4 o;
    o.x = f2bf(dx*inv*w4.x + b4.x);
    o.y = f2bf(dy*inv*w4.y + b4.y);
    o.z = f2bf(dz*inv*w4.z + b4.z);
    o.w = f2bf(dw*inv*w4.w + b4.w);
    ((ushort4*)(xn + row*Dv))[lane] = o;
}

// ---------------- final: LN + mask select (fp32 out) ------------------------
__global__ __launch_bounds__(256) void final_kernel(
    const float* __restrict__ x, const float* __restrict__ lat,
    const int* __restrict__ mask, const float* __restrict__ w,
    const float* __restrict__ b, float* __restrict__ out)
{
    int wv = threadIdx.x >> 6, lane = threadIdx.x & 63;
    size_t row = (size_t)blockIdx.x * 4 + wv;
    float4 v = ((const float4*)(x + row*Dv))[lane];
    float mu = wave_sum(v.x + v.y + v.z + v.w) * (1.0f/Dv);
    float dx = v.x-mu, dy = v.y-mu, dz = v.z-mu, dw = v.w-mu;
    float var = wave_sum(dx*dx + dy*dy + dz*dz + dw*dw) * (1.0f/Dv);
    float inv = rsqrtf(var + EPSv);
    float4 w4 = ((const float4*)w)[lane];
    float4 b4 = ((const float4*)b)[lane];
    float4 o;
    o.x = dx*inv*w4.x + b4.x;
    o.y = dy*inv*w4.y + b4.y;
    o.z = dz*inv*w4.z + b4.z;
    o.w = dw*inv*w4.w + b4.w;
    if (!mask[row]) o = ((const float4*)(lat + row*Dv))[lane];
    ((float4*)(out + row*Dv))[lane] = o;
}

// ---------------- bf16 MFMA GEMM (128x128 tile, BK=64, XOR-swizzled LDS) ----
template<int RELU>
__global__ __launch_bounds__(256) void mm_kernel(
    const us* __restrict__ A, const us* __restrict__ B,
    const float* __restrict__ bias, us* __restrict__ C,
    int M, int N, int K)
{
    __shared__ us As[128*64];
    __shared__ us Bs[128*64];
    int tid  = threadIdx.x;
    int lane = tid & 63;
    int wu   = __builtin_amdgcn_readfirstlane(tid >> 6);
    int m0 = blockIdx.x * 128, n0 = blockIdx.y * 128;
    int wm = wu & 1, wn = wu >> 1;
    f32x4 acc[4][4] = {};
    int srow = lane >> 3;
    int sg   = (lane & 7) ^ srow;
    const us* Ag = A + (size_t)m0 * K + sg*8;
    const us* Bg = B + (size_t)n0 * K + sg*8;
    int cc = lane & 15, q4 = lane >> 4;
    for (int k0 = 0; k0 < K; k0 += 64) {
        __syncthreads();
#pragma unroll
        for (int p = 0; p < 4; p++) {
            int row = wu*32 + p*8;
            __builtin_amdgcn_global_load_lds(
                (const __attribute__((address_space(1))) unsigned int*)(Ag + (size_t)(row + srow)*K + k0),
                (__attribute__((address_space(3))) unsigned int*)(As + row*64),
                16, 0, 0);
            __builtin_amdgcn_global_load_lds(
                (const __attribute__((address_space(1))) unsigned int*)(Bg + (size_t)(row + srow)*K + k0),
                (__attribute__((address_space(3))) unsigned int*)(Bs + row*64),
                16, 0, 0);
        }
        __syncthreads();
#pragma unroll
        for (int h = 0; h < 2; h++) {
            int pg = ((h*4 + q4) ^ (cc & 7)) * 8;
            short8 av[4], bv[4];
#pragma unroll
            for (int i = 0; i < 4; i++)
                av[i] = *(const short8*)(As + (wm*64 + i*16 + cc)*64 + pg);
#pragma unroll
            for (int j = 0; j < 4; j++)
                bv[j] = *(const short8*)(Bs + (wn*64 + j*16 + cc)*64 + pg);
#pragma unroll
            for (int i = 0; i < 4; i++)
#pragma unroll
                for (int j = 0; j < 4; j++)
                    acc[i][j] = __builtin_amdgcn_mfma_f32_16x16x32_bf16(av[i], bv[j], acc[i][j], 0, 0, 0);
        }
    }
#pragma unroll
    for (int j = 0; j < 4; j++) {
        int n = n0 + wn*64 + j*16 + cc;
        float bj = bias[n];
#pragma unroll
        for (int i = 0; i < 4; i++) {
#pragma unroll
            for (int r = 0; r < 4; r++) {
                int m = m0 + wm*64 + i*16 + q4*4 + r;
                float v = acc[i][j][r] + bj;
                if (RELU) v = fmaxf(v, 0.f);
                C[(size_t)m * N + n] = f2bf(v);
            }
        }
    }
}

// ---------------- GEMM 64xN=256 tile (BK=64, swizzled) + residual + fused LN
// K-generic: used for attn-out proj (K=256) AND ffn second GEMM (K=512).
__global__ __launch_bounds__(256) void mm256_kernel(
    const us* __restrict__ A, const us* __restrict__ B,
    const float* __restrict__ bias, float* __restrict__ x,
    us* __restrict__ xn, const float* __restrict__ nw,
    const float* __restrict__ nb, int M, int K)
{
    __shared__ us As[64*64];
    __shared__ us Bs[256*64];
    __shared__ float red[64][4][2];
    __shared__ float mus[64], rss[64];
    int tid  = threadIdx.x;
    int lane = tid & 63;
    int wu   = __builtin_amdgcn_readfirstlane(tid >> 6);
    int m0 = blockIdx.x * 64;
    f32x4 acc[4][4] = {};
    int srow = lane >> 3;
    int sg   = (lane & 7) ^ srow;
    const us* Ag = A + (size_t)m0 * K + sg*8;
    const us* Bg = B + sg*8;
    int cc = lane & 15, q4 = lane >> 4;
    for (int k0 = 0; k0 < K; k0 += 64) {
        __syncthreads();
#pragma unroll
        for (int p = 0; p < 2; p++) {
            int row = wu*16 + p*8;
            __builtin_amdgcn_global_load_lds(
                (const __attribute__((address_space(1))) unsigned int*)(Ag + (size_t)(row + srow)*K + k0),
                (__attribute__((address_space(3))) unsigned int*)(As + row*64),
                16, 0, 0);
        }
#pragma unroll
        for (int p = 0; p < 8; p++) {
            int row = wu*64 + p*8;
            __builtin_amdgcn_global_load_lds(
                (const __attribute__((address_space(1))) unsigned int*)(Bg + (size_t)(row + srow)*K + k0),
                (__attribute__((address_space(3))) unsigned int*)(Bs + row*64),
                16, 0, 0);
        }
        __syncthreads();
#pragma unroll
        for (int h = 0; h < 2; h++) {
            int pg = ((h*4 + q4) ^ (cc & 7)) * 8;
            short8 av[4], bv[4];
#pragma unroll
            for (int i = 0; i < 4; i++)
                av[i] = *(const short8*)(As + (i*16 + cc)*64 + pg);
#pragma unroll
            for (int j = 0; j < 4; j++)
                bv[j] = *(const short8*)(Bs + (wu*64 + j*16 + cc)*64 + pg);
#pragma unroll
            for (int i = 0; i < 4; i++)
#pragma unroll
                for (int j = 0; j < 4; j++)
                    acc[i][j] = __builtin_amdgcn_mfma_f32_16x16x32_bf16(av[i], bv[j], acc[i][j], 0, 0, 0);
        }
    }
    float bb[4], nwv[4], nbv[4];
#pragma unroll
    for (int j = 0; j < 4; j++) {
        int n = wu*64 + j*16 + cc;
        bb[j] = bias[n]; nwv[j] = nw[n]; nbv[j] = nb[n];
    }
#pragma unroll
    for (int i = 0; i < 4; i++) {
        float s[4] = {0.f,0.f,0.f,0.f}, sq[4] = {0.f,0.f,0.f,0.f};
#pragma unroll
        for (int j = 0; j < 4; j++) {
#pragma unroll
            for (int r = 0; r < 4; r++) {
                int m = m0 + i*16 + q4*4 + r;
                size_t off = (size_t)m * Dv + wu*64 + j*16 + cc;
                float v = acc[i][j][r] + bb[j] + x[off];
                acc[i][j][r] = v;
                x[off] = v;
                s[r] += v; sq[r] += v*v;
            }
        }
#pragma unroll
        for (int r = 0; r < 4; r++) {
#pragma unroll
            for (int o = 1; o < 16; o <<= 1) {
                s[r]  += __shfl_xor(s[r],  o);
                sq[r] += __shfl_xor(sq[r], o);
            }
        }
        if (cc == 0) {
#pragma unroll
            for (int r = 0; r < 4; r++) {
                red[i*16 + q4*4 + r][wu][0] = s[r];
                red[i*16 + q4*4 + r][wu][1] = sq[r];
            }
        }
    }
    __syncthreads();
    if (tid < 64) {
        float ts = red[tid][0][0] + red[tid][1][0] + red[tid][2][0] + red[tid][3][0];
        float tq = red[tid][0][1] + red[tid][1][1] + red[tid][2][1] + red[tid][3][1];
        float mu = ts * (1.0f/Dv);
        float var = tq * (1.0f/Dv) - mu*mu;
        mus[tid] = mu;
        rss[tid] = rsqrtf(var + EPSv);
    }
    __syncthreads();
#pragma unroll
    for (int i = 0; i < 4; i++) {
#pragma unroll
        for (int r = 0; r < 4; r++) {
            int ml = i*16 + q4*4 + r;
            float mu = mus[ml], rv = rss[ml];
#pragma unroll
            for (int j = 0; j < 4; j++) {
                size_t off = (size_t)(m0 + ml) * Dv + wu*64 + j*16 + cc;
                xn[off] = f2bf((acc[i][j][r] - mu)*rv*nwv[j] + nbv[j]);
            }
        }
    }
}

// ---------------- MFMA flash attention (S^T form, 2-deep pipelined) ---------
// XCD-aware decode: b = blk&63 so XCD (blk%8) hosts a fixed b%8 slice ->
// K/V working set per XCD ~ L2-sized.
__global__ __launch_bounds__(256) void attn_kernel(
    const us* __restrict__ qkv, us* __restrict__ ao)
{
    int blk = blockIdx.x;
    int b  = blk & 63;
    int h  = (blk >> 6) & 7;
    int qt = blk >> 9;
    int i0 = qt << 6;
    int tid = threadIdx.x;
    int lane = tid & 63;
    int wu = tid >> 6;

    __shared__ us Ks[2][64][40];
    __shared__ us Vt[2][32][72];
    __shared__ us Ps[4][16][72];
    __shared__ float Ls[4][16];

    size_t rowbase = (size_t)b * Tv;
    int c = lane & 15, q4 = lane >> 4;

    short8 qfrag = *(const short8*)(qkv + (rowbase + i0 + wu*16 + c)*768 + h*32 + q4*8);

    int skey = tid >> 2, sdc = (tid & 3) << 3;
    int vkey = tid & 63, vg = tid >> 6;
    const us* kgp = qkv + (rowbase + skey)*768 + 256 + h*32 + sdc;
    const us* vgp = qkv + (rowbase + vkey)*768 + 512 + h*32 + vg*8;

    f32x4 oacc[2] = {};
    float lsum = 0.f;
    int ntiles = qt + 1;

    short8 kreg = *(const short8*)(kgp);
    short8 vreg = *(const short8*)(vgp);
    *(short8*)&Ks[0][skey][sdc] = kreg;
#pragma unroll
    for (int j = 0; j < 8; j++) Vt[0][vg*8 + j][vkey] = vreg[j];
    if (ntiles > 1) {
        kreg = *(const short8*)(kgp + 64*768);
        vreg = *(const short8*)(vgp + 64*768);
    }
    __syncthreads();

    for (int kt = 0; kt < ntiles; kt++) {
        int cur = kt & 1;
        if (kt + 1 < ntiles) {
            *(short8*)&Ks[cur^1][skey][sdc] = kreg;
#pragma unroll
            for (int j = 0; j < 8; j++) Vt[cur^1][vg*8 + j][vkey] = vreg[j];
        }
        if (kt + 2 < ntiles) {
            kreg = *(const short8*)(kgp + (size_t)(kt+2)*64*768);
            vreg = *(const short8*)(vgp + (size_t)(kt+2)*64*768);
        }

        f32x4 st[4];
#pragma unroll
        for (int jt = 0; jt < 4; jt++) {
            short8 kf = *(const short8*)&Ks[cur][jt*16 + c][q4*8];
            st[jt] = __builtin_amdgcn_mfma_f32_16x16x32_bf16(kf, qfrag, (f32x4){0.f,0.f,0.f,0.f}, 0, 0, 0);
        }
        bool diag = (kt == ntiles - 1);
#pragma unroll
        for (int jt = 0; jt < 4; jt++) {
            float msk = (!diag || (2*jt + (q4 >> 1) <= 2*wu + (c >> 3))) ? 1.f : 0.f;
            float p0 = __expf(st[jt][0]) * msk;
            float p1 = __expf(st[jt][1]) * msk;
            float p2 = __expf(st[jt][2]) * msk;
            float p3 = __expf(st[jt][3]) * msk;
            lsum += p0 + p1 + p2 + p3;
            uint2 w2; w2.x = pk2(p0, p1); w2.y = pk2(p2, p3);
            *(uint2*)&Ps[wu][c][jt*16 + q4*4] = w2;
        }
#pragma unroll
        for (int kk = 0; kk < 2; kk++) {
            short8 pf = *(const short8*)&Ps[wu][c][kk*32 + q4*8];
#pragma unroll
            for (int dt = 0; dt < 2; dt++) {
                short8 vf = *(const short8*)&Vt[cur][dt*16 + c][kk*32 + q4*8];
                oacc[dt] = __builtin_amdgcn_mfma_f32_16x16x32_bf16(pf, vf, oacc[dt], 0, 0, 0);
            }
        }
        __syncthreads();
    }

    float l = lsum;
    l += __shfl_xor(l, 16);
    l += __shfl_xor(l, 32);
    if (q4 == 0) Ls[wu][c] = 1.0f / l;
    float4 lv4 = *(const float4*)&Ls[wu][q4*4];
#pragma unroll
    for (int dt = 0; dt < 2; dt++) {
#pragma unroll
        for (int r = 0; r < 4; r++) {
            float li = (r == 0) ? lv4.x : (r == 1) ? lv4.y : (r == 2) ? lv4.z : lv4.w;
            ao[(rowbase + i0 + wu*16 + q4*4 + r)*256 + h*32 + dt*16 + c] = f2bf(oacc[dt][r] * li);
        }
    }
}

// ---------------- launch ----------------------------------------------------
extern "C" void kernel_launch(void* const* d_in, const int* in_sizes, int n_in,
                              void* d_out, int out_size, void* d_ws, size_t ws_size,
                              hipStream_t stream)
{
    const float* latents    = (const float*)d_in[0];
    const int*   move_ids   = (const int*)  d_in[1];
    const int*   mask       = (const int*)  d_in[2];
    const float* positional = (const float*)d_in[3];
    const float* embed_from = (const float*)d_in[4];
    const float* embed_to   = (const float*)d_in[5];
    const float* embed_promo= (const float*)d_in[6];
    const float* in_proj_w  = (const float*)d_in[7];
    const float* in_proj_b  = (const float*)d_in[8];
    const float* out_w      = (const float*)d_in[9];
    const float* out_b      = (const float*)d_in[10];
    const float* fc1_w      = (const float*)d_in[11];
    const float* fc1_b      = (const float*)d_in[12];
    const float* fc2_w      = (const float*)d_in[13];
    const float* fc2_b      = (const float*)d_in[14];
    const float* norm_w     = (const float*)d_in[15];
    const float* norm_b     = (const float*)d_in[16];
    float* out = (float*)d_out;

    float* x   = (float*)d_ws;                              // BT*256 f32
    float* sb  = x + (size_t)BTv * Dv;                      // L*768 f32
    us* xn  = (us*)(sb + Lv*768);                           // BT*256 bf16
    us* qkv = xn + (size_t)BTv * Dv;                        // BT*768
    us* ao  = qkv + (size_t)BTv * 768;                      // BT*256
    us* h1  = ao + (size_t)BTv * Dv;                        // BT*512 bf16 (ffn intermediate)
    us* wq  = h1 + (size_t)BTv * FFv;                       // L*768*256
    us* wo  = wq + (size_t)Lv * 768 * Dv;
    us* w1  = wo + (size_t)Lv * Dv * Dv;
    us* w2  = w1 + (size_t)Lv * FFv * Dv;

    cvtall_kernel<<<2060, 256, 0, stream>>>(in_proj_w, out_w, fc1_w, fc2_w,
                                            in_proj_b, wq, wo, w1, w2, sb);

    embed_ln_kernel<<<BTv/4, 256, 0, stream>>>(latents, move_ids, positional,
        embed_from, embed_to, embed_promo, norm_w, norm_b, x, xn);

    for (int l = 0; l < Lv; l++) {
        mm_kernel<0><<<dim3(BTv/128, 768/128), 256, 0, stream>>>(
            xn, wq + (size_t)l*768*Dv, sb + l*768, qkv, BTv, 768, Dv);
        attn_kernel<<<Bv*8*(Tv/64), 256, 0, stream>>>(qkv, ao);
        mm256_kernel<<<BTv/64, 256, 0, stream>>>(
            ao, wo + (size_t)l*Dv*Dv, out_b + l*Dv, x, xn, norm_w, norm_b,
            BTv, Dv);
        // FFN phase 1: h1 = relu(xn @ W1^T + b1)  (128x128 tile, 3 blocks/CU)
        mm_kernel<1><<<dim3(BTv/128, FFv/128), 256, 0, stream>>>(
            xn, w1 + (size_t)l*FFv*Dv, fc1_b + l*FFv, h1, BTv, FFv, Dv);
        // FFN phase 2: x += h1 @ W2^T + b2 ; xn = LN(x)  (K=512)
        mm256_kernel<<<BTv/64, 256, 0, stream>>>(
            h1, w2 + (size_t)l*Dv*FFv, fc2_b + l*Dv, x, xn, norm_w, norm_b,
            BTv, FFv);
    }
    final_kernel<<<BTv/4, 256, 0, stream>>>(x, latents, mask, norm_w, norm_b, out);
}

// Round 4
// 628.704 us; speedup vs baseline: 1.5601x; 1.0301x over previous
//
#include <hip/hip_runtime.h>
#include <math.h>

#define Bv  64
#define Tv  512
#define Dv  256
#define FFv 512
#define Lv  4
#define BTv (Bv*Tv)
#define EPSv 1e-5f
// Q scale: 1/sqrt(32) * log2(e)  (log2e folded so attn uses raw v_exp_f32 = 2^x)
#define QSC 0.25509402f

typedef __attribute__((ext_vector_type(8))) short short8;
typedef __attribute__((ext_vector_type(4))) float f32x4;
typedef unsigned short us;

#if __has_builtin(__builtin_amdgcn_exp2f)
#define EXP2(x) __builtin_amdgcn_exp2f(x)
#else
#define EXP2(x) exp2f(x)
#endif

// single f32 -> bf16 (RNE) via v_cvt_pk_bf16_f32, 1 VALU inst
__device__ __forceinline__ us f2bf(float f) {
    unsigned r;
    asm("v_cvt_pk_bf16_f32 %0, %1, 0" : "=v"(r) : "v"(f));
    return (us)r;
}
// pack two f32 -> 2x bf16 (lo=a, hi=b), 1 VALU inst
__device__ __forceinline__ unsigned pk2(float a, float b) {
    unsigned r;
    asm("v_cvt_pk_bf16_f32 %0, %1, %2" : "=v"(r) : "v"(a), "v"(b));
    return r;
}
__device__ __forceinline__ float wave_sum(float v) {
#pragma unroll
    for (int o = 32; o > 0; o >>= 1) v += __shfl_xor(v, o);
    return v;
}

// ---------------- all weight converts in one launch -------------------------
__global__ __launch_bounds__(256) void cvtall_kernel(
    const float* __restrict__ qw, const float* __restrict__ ow,
    const float* __restrict__ f1, const float* __restrict__ f2,
    const float* __restrict__ qb,
    us* __restrict__ wq, us* __restrict__ wo, us* __restrict__ w1,
    us* __restrict__ w2, float* __restrict__ sb)
{
    int blk = blockIdx.x, tid = threadIdx.x;
    if (blk < 2048) {
        const float* s; us* d; int i; float sc = 1.0f;
        if (blk < 768)       { i = blk*256 + tid;        s = qw; d = wq;
                               sc = (((i >> 6) % 768) < 256) ? QSC : 1.0f; }
        else if (blk < 1024) { i = (blk-768)*256 + tid;  s = ow; d = wo; }
        else if (blk < 1536) { i = (blk-1024)*256 + tid; s = f1; d = w1; }
        else                 { i = (blk-1536)*256 + tid; s = f2; d = w2; }
        float4 v = ((const float4*)s)[i];
        uint2 o;
        o.x = pk2(v.x*sc, v.y*sc);
        o.y = pk2(v.z*sc, v.w*sc);
        ((uint2*)d)[i] = o;
    } else {
        int i = (blk-2048)*256 + tid;
        sb[i] = qb[i] * (((i % 768) < 256) ? QSC : 1.0f);
    }
}

// ---------------- embed + LN: 4 rows/block, one wave per row, float4 --------
__global__ __launch_bounds__(256) void embed_ln_kernel(
    const float* __restrict__ lat, const int* __restrict__ mids,
    const float* __restrict__ pos, const float* __restrict__ ef,
    const float* __restrict__ et,  const float* __restrict__ ep,
    const float* __restrict__ nw,  const float* __restrict__ nb,
    float* __restrict__ x, us* __restrict__ xn)
{
    int wv = threadIdx.x >> 6, lane = threadIdx.x & 63;
    size_t row = (size_t)blockIdx.x * 4 + wv;
    int t  = (int)(row & (Tv - 1));
    int id = mids[row];
    int promo = id >> 12;
    int rem   = id & 4095;
    int frm   = rem >> 6;
    int to    = rem & 63;
    float4 v  = ((const float4*)(lat + row*Dv))[lane];
    float4 pv = ((const float4*)(pos + (size_t)t*Dv))[lane];
    float4 fv = ((const float4*)(ef + (size_t)frm*Dv))[lane];
    float4 tv = ((const float4*)(et + (size_t)to*Dv))[lane];
    float4 ev = ((const float4*)(ep + (size_t)promo*Dv))[lane];
    v.x += pv.x + fv.x + tv.x + ev.x;
    v.y += pv.y + fv.y + tv.y + ev.y;
    v.z += pv.z + fv.z + tv.z + ev.z;
    v.w += pv.w + fv.w + tv.w + ev.w;
    ((float4*)(x + row*Dv))[lane] = v;
    float mu = wave_sum(v.x + v.y + v.z + v.w) * (1.0f/Dv);
    float dx = v.x-mu, dy = v.y-mu, dz = v.z-mu, dw = v.w-mu;
    float var = wave_sum(dx*dx + dy*dy + dz*dz + dw*dw) * (1.0f/Dv);
    float inv = rsqrtf(var + EPSv);
    float4 w4 = ((const float4*)nw)[lane];
    float4 b4 = ((const float4*)nb)[lane];
    uint2 o;
    o.x = pk2(dx*inv*w4.x + b4.x, dy*inv*w4.y + b4.y);
    o.y = pk2(dz*inv*w4.z + b4.z, dw*inv*w4.w + b4.w);
    ((uint2*)(xn + row*Dv))[lane] = o;
}

// ---------------- final: LN + mask select (fp32 out) ------------------------
__global__ __launch_bounds__(256) void final_kernel(
    const float* __restrict__ x, const float* __restrict__ lat,
    const int* __restrict__ mask, const float* __restrict__ w,
    const float* __restrict__ b, float* __restrict__ out)
{
    int wv = threadIdx.x >> 6, lane = threadIdx.x & 63;
    size_t row = (size_t)blockIdx.x * 4 + wv;
    float4 v = ((const float4*)(x + row*Dv))[lane];
    float mu = wave_sum(v.x + v.y + v.z + v.w) * (1.0f/Dv);
    float dx = v.x-mu, dy = v.y-mu, dz = v.z-mu, dw = v.w-mu;
    float var = wave_sum(dx*dx + dy*dy + dz*dz + dw*dw) * (1.0f/Dv);
    float inv = rsqrtf(var + EPSv);
    float4 w4 = ((const float4*)w)[lane];
    float4 b4 = ((const float4*)b)[lane];
    float4 o;
    o.x = dx*inv*w4.x + b4.x;
    o.y = dy*inv*w4.y + b4.y;
    o.z = dz*inv*w4.z + b4.z;
    o.w = dw*inv*w4.w + b4.w;
    if (!mask[row]) o = ((const float4*)(lat + row*Dv))[lane];
    ((float4*)(out + row*Dv))[lane] = o;
}

// ---------------- bf16 MFMA GEMM (128x128 tile, BK=64, XOR-swizzled LDS) ----
template<int RELU>
__global__ __launch_bounds__(256) void mm_kernel(
    const us* __restrict__ A, const us* __restrict__ B,
    const float* __restrict__ bias, us* __restrict__ C,
    int M, int N, int K)
{
    __shared__ us As[128*64];
    __shared__ us Bs[128*64];
    int tid  = threadIdx.x;
    int lane = tid & 63;
    int wu   = __builtin_amdgcn_readfirstlane(tid >> 6);
    int m0 = blockIdx.x * 128, n0 = blockIdx.y * 128;
    int wm = wu & 1, wn = wu >> 1;
    f32x4 acc[4][4] = {};
    int srow = lane >> 3;
    int sg   = (lane & 7) ^ srow;
    const us* Ag = A + (size_t)m0 * K + sg*8;
    const us* Bg = B + (size_t)n0 * K + sg*8;
    int cc = lane & 15, q4 = lane >> 4;
    for (int k0 = 0; k0 < K; k0 += 64) {
        __syncthreads();
#pragma unroll
        for (int p = 0; p < 4; p++) {
            int row = wu*32 + p*8;
            __builtin_amdgcn_global_load_lds(
                (const __attribute__((address_space(1))) unsigned int*)(Ag + (size_t)(row + srow)*K + k0),
                (__attribute__((address_space(3))) unsigned int*)(As + row*64),
                16, 0, 0);
            __builtin_amdgcn_global_load_lds(
                (const __attribute__((address_space(1))) unsigned int*)(Bg + (size_t)(row + srow)*K + k0),
                (__attribute__((address_space(3))) unsigned int*)(Bs + row*64),
                16, 0, 0);
        }
        __syncthreads();
#pragma unroll
        for (int h = 0; h < 2; h++) {
            int pg = ((h*4 + q4) ^ (cc & 7)) * 8;
            short8 av[4], bv[4];
#pragma unroll
            for (int i = 0; i < 4; i++)
                av[i] = *(const short8*)(As + (wm*64 + i*16 + cc)*64 + pg);
#pragma unroll
            for (int j = 0; j < 4; j++)
                bv[j] = *(const short8*)(Bs + (wn*64 + j*16 + cc)*64 + pg);
#pragma unroll
            for (int i = 0; i < 4; i++)
#pragma unroll
                for (int j = 0; j < 4; j++)
                    acc[i][j] = __builtin_amdgcn_mfma_f32_16x16x32_bf16(av[i], bv[j], acc[i][j], 0, 0, 0);
        }
    }
#pragma unroll
    for (int j = 0; j < 4; j++) {
        int n = n0 + wn*64 + j*16 + cc;
        float bj = bias[n];
#pragma unroll
        for (int i = 0; i < 4; i++) {
#pragma unroll
            for (int r = 0; r < 4; r++) {
                int m = m0 + wm*64 + i*16 + q4*4 + r;
                float v = acc[i][j][r] + bj;
                if (RELU) v = fmaxf(v, 0.f);
                C[(size_t)m * N + n] = f2bf(v);
            }
        }
    }
}

// ---------------- GEMM 64xN=256 tile (BK=64, swizzled) + residual + fused LN
// K-generic: used for attn-out proj (K=256) AND ffn second GEMM (K=512).
__global__ __launch_bounds__(256) void mm256_kernel(
    const us* __restrict__ A, const us* __restrict__ B,
    const float* __restrict__ bias, float* __restrict__ x,
    us* __restrict__ xn, const float* __restrict__ nw,
    const float* __restrict__ nb, int M, int K)
{
    __shared__ us As[64*64];
    __shared__ us Bs[256*64];
    __shared__ float red[64][4][2];
    __shared__ float mus[64], rss[64];
    int tid  = threadIdx.x;
    int lane = tid & 63;
    int wu   = __builtin_amdgcn_readfirstlane(tid >> 6);
    int m0 = blockIdx.x * 64;
    f32x4 acc[4][4] = {};
    int srow = lane >> 3;
    int sg   = (lane & 7) ^ srow;
    const us* Ag = A + (size_t)m0 * K + sg*8;
    const us* Bg = B + sg*8;
    int cc = lane & 15, q4 = lane >> 4;
    for (int k0 = 0; k0 < K; k0 += 64) {
        __syncthreads();
#pragma unroll
        for (int p = 0; p < 2; p++) {
            int row = wu*16 + p*8;
            __builtin_amdgcn_global_load_lds(
                (const __attribute__((address_space(1))) unsigned int*)(Ag + (size_t)(row + srow)*K + k0),
                (__attribute__((address_space(3))) unsigned int*)(As + row*64),
                16, 0, 0);
        }
#pragma unroll
        for (int p = 0; p < 8; p++) {
            int row = wu*64 + p*8;
            __builtin_amdgcn_global_load_lds(
                (const __attribute__((address_space(1))) unsigned int*)(Bg + (size_t)(row + srow)*K + k0),
                (__attribute__((address_space(3))) unsigned int*)(Bs + row*64),
                16, 0, 0);
        }
        __syncthreads();
#pragma unroll
        for (int h = 0; h < 2; h++) {
            int pg = ((h*4 + q4) ^ (cc & 7)) * 8;
            short8 av[4], bv[4];
#pragma unroll
            for (int i = 0; i < 4; i++)
                av[i] = *(const short8*)(As + (i*16 + cc)*64 + pg);
#pragma unroll
            for (int j = 0; j < 4; j++)
                bv[j] = *(const short8*)(Bs + (wu*64 + j*16 + cc)*64 + pg);
#pragma unroll
            for (int i = 0; i < 4; i++)
#pragma unroll
                for (int j = 0; j < 4; j++)
                    acc[i][j] = __builtin_amdgcn_mfma_f32_16x16x32_bf16(av[i], bv[j], acc[i][j], 0, 0, 0);
        }
    }
    float bb[4], nwv[4], nbv[4];
#pragma unroll
    for (int j = 0; j < 4; j++) {
        int n = wu*64 + j*16 + cc;
        bb[j] = bias[n]; nwv[j] = nw[n]; nbv[j] = nb[n];
    }
#pragma unroll
    for (int i = 0; i < 4; i++) {
        float s[4] = {0.f,0.f,0.f,0.f}, sq[4] = {0.f,0.f,0.f,0.f};
#pragma unroll
        for (int j = 0; j < 4; j++) {
#pragma unroll
            for (int r = 0; r < 4; r++) {
                int m = m0 + i*16 + q4*4 + r;
                size_t off = (size_t)m * Dv + wu*64 + j*16 + cc;
                float v = acc[i][j][r] + bb[j] + x[off];
                acc[i][j][r] = v;
                x[off] = v;
                s[r] += v; sq[r] += v*v;
            }
        }
#pragma unroll
        for (int r = 0; r < 4; r++) {
#pragma unroll
            for (int o = 1; o < 16; o <<= 1) {
                s[r]  += __shfl_xor(s[r],  o);
                sq[r] += __shfl_xor(sq[r], o);
            }
        }
        if (cc == 0) {
#pragma unroll
            for (int r = 0; r < 4; r++) {
                red[i*16 + q4*4 + r][wu][0] = s[r];
                red[i*16 + q4*4 + r][wu][1] = sq[r];
            }
        }
    }
    __syncthreads();
    if (tid < 64) {
        float ts = red[tid][0][0] + red[tid][1][0] + red[tid][2][0] + red[tid][3][0];
        float tq = red[tid][0][1] + red[tid][1][1] + red[tid][2][1] + red[tid][3][1];
        float mu = ts * (1.0f/Dv);
        float var = tq * (1.0f/Dv) - mu*mu;
        mus[tid] = mu;
        rss[tid] = rsqrtf(var + EPSv);
    }
    __syncthreads();
#pragma unroll
    for (int i = 0; i < 4; i++) {
#pragma unroll
        for (int r = 0; r < 4; r++) {
            int ml = i*16 + q4*4 + r;
            float mu = mus[ml], rv = rss[ml];
#pragma unroll
            for (int j = 0; j < 4; j++) {
                size_t off = (size_t)(m0 + ml) * Dv + wu*64 + j*16 + cc;
                xn[off] = f2bf((acc[i][j][r] - mu)*rv*nwv[j] + nbv[j]);
            }
        }
    }
}

// ---------------- MFMA flash attention (S^T form, 2-deep pipelined) ---------
// Q pre-scaled by 1/sqrt(32)*log2e -> softmax numerator = exp2(s) (raw v_exp).
__global__ __launch_bounds__(256) void attn_kernel(
    const us* __restrict__ qkv, us* __restrict__ ao)
{
    int blk = blockIdx.x;
    int b  = blk & 63;
    int h  = (blk >> 6) & 7;
    int qt = blk >> 9;
    int i0 = qt << 6;
    int tid = threadIdx.x;
    int lane = tid & 63;
    int wu = tid >> 6;

    __shared__ us Ks[2][64][40];
    __shared__ us Vt[2][32][72];
    __shared__ us Ps[4][16][72];
    __shared__ float Ls[4][16];

    size_t rowbase = (size_t)b * Tv;
    int c = lane & 15, q4 = lane >> 4;

    short8 qfrag = *(const short8*)(qkv + (rowbase + i0 + wu*16 + c)*768 + h*32 + q4*8);

    int skey = tid >> 2, sdc = (tid & 3) << 3;
    int vkey = tid & 63, vg = tid >> 6;
    const us* kgp = qkv + (rowbase + skey)*768 + 256 + h*32 + sdc;
    const us* vgp = qkv + (rowbase + vkey)*768 + 512 + h*32 + vg*8;

    f32x4 oacc[2] = {};
    float lsum = 0.f;
    int ntiles = qt + 1;

    short8 kreg = *(const short8*)(kgp);
    short8 vreg = *(const short8*)(vgp);
    *(short8*)&Ks[0][skey][sdc] = kreg;
#pragma unroll
    for (int j = 0; j < 8; j++) Vt[0][vg*8 + j][vkey] = vreg[j];
    if (ntiles > 1) {
        kreg = *(const short8*)(kgp + 64*768);
        vreg = *(const short8*)(vgp + 64*768);
    }
    __syncthreads();

    for (int kt = 0; kt < ntiles; kt++) {
        int cur = kt & 1;
        if (kt + 1 < ntiles) {
            *(short8*)&Ks[cur^1][skey][sdc] = kreg;
#pragma unroll
            for (int j = 0; j < 8; j++) Vt[cur^1][vg*8 + j][vkey] = vreg[j];
        }
        if (kt + 2 < ntiles) {
            kreg = *(const short8*)(kgp + (size_t)(kt+2)*64*768);
            vreg = *(const short8*)(vgp + (size_t)(kt+2)*64*768);
        }

        f32x4 st[4];
#pragma unroll
        for (int jt = 0; jt < 4; jt++) {
            short8 kf = *(const short8*)&Ks[cur][jt*16 + c][q4*8];
            st[jt] = __builtin_amdgcn_mfma_f32_16x16x32_bf16(kf, qfrag, (f32x4){0.f,0.f,0.f,0.f}, 0, 0, 0);
        }
        bool diag = (kt == ntiles - 1);
#pragma unroll
        for (int jt = 0; jt < 4; jt++) {
            float msk = (!diag || (2*jt + (q4 >> 1) <= 2*wu + (c >> 3))) ? 1.f : 0.f;
            float p0 = EXP2(st[jt][0]) * msk;
            float p1 = EXP2(st[jt][1]) * msk;
            float p2 = EXP2(st[jt][2]) * msk;
            float p3 = EXP2(st[jt][3]) * msk;
            lsum += p0 + p1 + p2 + p3;
            uint2 w2; w2.x = pk2(p0, p1); w2.y = pk2(p2, p3);
            *(uint2*)&Ps[wu][c][jt*16 + q4*4] = w2;
        }
#pragma unroll
        for (int kk = 0; kk < 2; kk++) {
            short8 pf = *(const short8*)&Ps[wu][c][kk*32 + q4*8];
#pragma unroll
            for (int dt = 0; dt < 2; dt++) {
                short8 vf = *(const short8*)&Vt[cur][dt*16 + c][kk*32 + q4*8];
                oacc[dt] = __builtin_amdgcn_mfma_f32_16x16x32_bf16(pf, vf, oacc[dt], 0, 0, 0);
            }
        }
        __syncthreads();
    }

    float l = lsum;
    l += __shfl_xor(l, 16);
    l += __shfl_xor(l, 32);
    if (q4 == 0) Ls[wu][c] = 1.0f / l;
    float4 lv4 = *(const float4*)&Ls[wu][q4*4];
#pragma unroll
    for (int dt = 0; dt < 2; dt++) {
#pragma unroll
        for (int r = 0; r < 4; r++) {
            float li = (r == 0) ? lv4.x : (r == 1) ? lv4.y : (r == 2) ? lv4.z : lv4.w;
            ao[(rowbase + i0 + wu*16 + q4*4 + r)*256 + h*32 + dt*16 + c] = f2bf(oacc[dt][r] * li);
        }
    }
}

// ---------------- launch ----------------------------------------------------
extern "C" void kernel_launch(void* const* d_in, const int* in_sizes, int n_in,
                              void* d_out, int out_size, void* d_ws, size_t ws_size,
                              hipStream_t stream)
{
    const float* latents    = (const float*)d_in[0];
    const int*   move_ids   = (const int*)  d_in[1];
    const int*   mask       = (const int*)  d_in[2];
    const float* positional = (const float*)d_in[3];
    const float* embed_from = (const float*)d_in[4];
    const float* embed_to   = (const float*)d_in[5];
    const float* embed_promo= (const float*)d_in[6];
    const float* in_proj_w  = (const float*)d_in[7];
    const float* in_proj_b  = (const float*)d_in[8];
    const float* out_w      = (const float*)d_in[9];
    const float* out_b      = (const float*)d_in[10];
    const float* fc1_w      = (const float*)d_in[11];
    const float* fc1_b      = (const float*)d_in[12];
    const float* fc2_w      = (const float*)d_in[13];
    const float* fc2_b      = (const float*)d_in[14];
    const float* norm_w     = (const float*)d_in[15];
    const float* norm_b     = (const float*)d_in[16];
    float* out = (float*)d_out;

    float* x   = (float*)d_ws;                              // BT*256 f32
    float* sb  = x + (size_t)BTv * Dv;                      // L*768 f32
    us* xn  = (us*)(sb + Lv*768);                           // BT*256 bf16
    us* qkv = xn + (size_t)BTv * Dv;                        // BT*768
    us* ao  = qkv + (size_t)BTv * 768;                      // BT*256
    us* h1  = ao + (size_t)BTv * Dv;                        // BT*512 bf16 (ffn intermediate)
    us* wq  = h1 + (size_t)BTv * FFv;                       // L*768*256
    us* wo  = wq + (size_t)Lv * 768 * Dv;
    us* w1  = wo + (size_t)Lv * Dv * Dv;
    us* w2  = w1 + (size_t)Lv * FFv * Dv;

    cvtall_kernel<<<2060, 256, 0, stream>>>(in_proj_w, out_w, fc1_w, fc2_w,
                                            in_proj_b, wq, wo, w1, w2, sb);

    embed_ln_kernel<<<BTv/4, 256, 0, stream>>>(latents, move_ids, positional,
        embed_from, embed_to, embed_promo, norm_w, norm_b, x, xn);

    for (int l = 0; l < Lv; l++) {
        mm_kernel<0><<<dim3(BTv/128, 768/128), 256, 0, stream>>>(
            xn, wq + (size_t)l*768*Dv, sb + l*768, qkv, BTv, 768, Dv);
        attn_kernel<<<Bv*8*(Tv/64), 256, 0, stream>>>(qkv, ao);
        mm256_kernel<<<BTv/64, 256, 0, stream>>>(
            ao, wo + (size_t)l*Dv*Dv, out_b + l*Dv, x, xn, norm_w, norm_b,
            BTv, Dv);
        // FFN phase 1: h1 = relu(xn @ W1^T + b1)  (128x128 tile)
        mm_kernel<1><<<dim3(BTv/128, FFv/128), 256, 0, stream>>>(
            xn, w1 + (size_t)l*FFv*Dv, fc1_b + l*FFv, h1, BTv, FFv, Dv);
        // FFN phase 2: x += h1 @ W2^T + b2 ; xn = LN(x)  (K=512)
        mm256_kernel<<<BTv/64, 256, 0, stream>>>(
            h1, w2 + (size_t)l*Dv*FFv, fc2_b + l*Dv, x, xn, norm_w, norm_b,
            BTv, FFv);
    }
    final_kernel<<<BTv/4, 256, 0, stream>>>(x, latents, mask, norm_w, norm_b, out);
}